// Round 5
// baseline (128.313 us; speedup 1.0000x reference)
//
#include <hip/hip_runtime.h>

// QueryAndGroupRRI: B=4, N=16384, M=2048, nsample=32, radius=0.1
// Inputs (float32): xyz (4,16384,3), new_xyz (4,2048,3)
// Output (float32): (4, 33, 2048, 32)  [dis_sort rows 0..31, grouped_r row 32]
//
// Strategy: 10^3 uniform grid (cell = r = 0.1) over xyz -> candidates from 27
// cells (~442 vs ~10000 brute-force). Hits collected unordered into LDS, then
// 32 smallest indices selected via 128-wide register bitonic (key = idx<<8|slot).
// Downstream geometry identical to the verified brute-force version.

#define BB 4
#define NN 16384
#define MM 2048
#define NS 32
#define R2 0.01f   // fp32-nearest of 0.1*0.1
#define GCD 10
#define NCELL 1000
#define CPAD 1024
#define HCAP 128   // per-query hit cap (lambda~68, P(>128)~1e-13)

// ws layout: [0,16K) cnt int[4][1024] | [16K,32K) off | [32K,48K) cur
//            [48K, 48K+1M) pts float4[4][16384]
#define WS_OFF_OFF (16 * 1024)
#define WS_CUR_OFF (32 * 1024)
#define WS_PTS_OFF (48 * 1024)
#define WS_NEED (WS_PTS_OFF + (size_t)BB * NN * 16)

__device__ __forceinline__ int cell_of(float x, float y, float z) {
    int ci = (int)(x * 10.0f); ci = ci < 0 ? 0 : (ci > 9 ? 9 : ci);
    int cj = (int)(y * 10.0f); cj = cj < 0 ? 0 : (cj > 9 ? 9 : cj);
    int ck = (int)(z * 10.0f); ck = ck < 0 ? 0 : (ck > 9 ? 9 : ck);
    return (ci * 10 + cj) * 10 + ck;
}

__global__ __launch_bounds__(256) void k_count(const float* __restrict__ xyz,
                                               int* __restrict__ cnt) {
    int i = blockIdx.x * 256 + threadIdx.x;  // 0..65535
    int b = i >> 14;
    const float* p = xyz + (size_t)i * 3;
    atomicAdd(&cnt[b * CPAD + cell_of(p[0], p[1], p[2])], 1);
}

__global__ __launch_bounds__(1024) void k_scan(const int* __restrict__ cnt,
                                               int* __restrict__ off,
                                               int* __restrict__ cur) {
    __shared__ int a[1024];
    int b = blockIdx.x, t = threadIdx.x;
    int v = (t < NCELL) ? cnt[b * CPAD + t] : 0;
    a[t] = v;
    __syncthreads();
    for (int s = 1; s < 1024; s <<= 1) {
        int u = (t >= s) ? a[t - s] : 0;
        __syncthreads();
        a[t] += u;
        __syncthreads();
    }
    int e = a[t] - v;  // exclusive
    if (t < NCELL) { off[b * CPAD + t] = e; cur[b * CPAD + t] = e; }
    if (t == NCELL - 1) off[b * CPAD + NCELL] = a[t];
}

__global__ __launch_bounds__(256) void k_scatter(const float* __restrict__ xyz,
                                                 int* __restrict__ cur,
                                                 float4* __restrict__ pts) {
    int i = blockIdx.x * 256 + threadIdx.x;
    int b = i >> 14;
    const float* p = xyz + (size_t)i * 3;
    float x = p[0], y = p[1], z = p[2];
    int pos = atomicAdd(&cur[b * CPAD + cell_of(x, y, z)], 1);
    pts[(size_t)b * NN + pos] = make_float4(x, y, z, __int_as_float(i & (NN - 1)));
}

__global__ __launch_bounds__(256) void qgr_grid_kernel(
    const float* __restrict__ xyz,
    const float* __restrict__ nxyz,
    const int* __restrict__ offi,
    const float4* __restrict__ pts,
    float* __restrict__ out) {

    __shared__ float4 s_hit[4][HCAP];                 // 8 KB
    __shared__ float s_gx[4][NS], s_gy[4][NS], s_gz[4][NS];
    __shared__ float s_dis[4][NS][NS + 1];            // stride 33: no bank conflict

    const int lane = threadIdx.x & 63;
    const int w = threadIdx.x >> 6;
    const int q = blockIdx.x * 4 + w;
    const int b = q >> 11;
    const int m = q & (MM - 1);

    const float* xb = xyz + (size_t)b * NN * 3;
    const float* nq = nxyz + (size_t)q * 3;
    const float cx = nq[0], cy = nq[1], cz = nq[2];
    const unsigned long long lmask = (1ull << lane) - 1ull;

    const int* offb = offi + b * CPAD;
    const float4* ptsb = pts + (size_t)b * NN;

    // ---- gather in-ball hits from 27 neighbor cells (unordered) ----
    int ci0 = (int)(cx * 10.0f); ci0 = ci0 < 0 ? 0 : (ci0 > 9 ? 9 : ci0);
    int cj0 = (int)(cy * 10.0f); cj0 = cj0 < 0 ? 0 : (cj0 > 9 ? 9 : cj0);
    int ck0 = (int)(cz * 10.0f); ck0 = ck0 < 0 ? 0 : (ck0 > 9 ? 9 : ck0);

    int hits = 0;
    for (int di = -1; di <= 1; ++di) {
        int ii = ci0 + di; if ((unsigned)ii > 9u) continue;
        for (int dj = -1; dj <= 1; ++dj) {
            int jj = cj0 + dj; if ((unsigned)jj > 9u) continue;
            for (int dk = -1; dk <= 1; ++dk) {
                int kk = ck0 + dk; if ((unsigned)kk > 9u) continue;
                int cell = (ii * 10 + jj) * 10 + kk;
                int s0 = offb[cell];
                int len = offb[cell + 1] - s0;
                for (int t0 = 0; t0 < len; t0 += 64) {   // wave-uniform rounds
                    int t = t0 + lane;
                    bool act = t < len;
                    float4 P = ptsb[s0 + (act ? t : 0)];
                    float dx = __fsub_rn(cx, P.x);
                    float dy = __fsub_rn(cy, P.y);
                    float dz = __fsub_rn(cz, P.z);
                    float d2 = __fadd_rn(__fadd_rn(__fmul_rn(dx, dx), __fmul_rn(dy, dy)),
                                         __fmul_rn(dz, dz));
                    bool hit = act && (d2 < R2);
                    unsigned long long bal = __ballot(hit);
                    if (bal) {
                        int rank = __popcll(bal & lmask);
                        int slot = hits + rank;
                        if (hit && slot < HCAP) s_hit[w][slot] = P;
                        hits += __popcll(bal);
                    }
                }
            }
        }
    }

    // ---- select 32 smallest indices: 128-elem register bitonic over the wave ----
    int cap = hits < HCAP ? hits : HCAP;
    int i0 = __float_as_int(s_hit[w][lane].w);
    int i1 = __float_as_int(s_hit[w][64 + lane].w);
    int key0 = (lane < cap)      ? ((i0 << 8) | lane)       : 0x7fffffff;
    int key1 = (64 + lane < cap) ? ((i1 << 8) | (64 + lane)) : 0x7fffffff;

    #pragma unroll
    for (int k = 2; k <= 128; k <<= 1) {
        #pragma unroll
        for (int j = k >> 1; j > 0; j >>= 1) {
            if (j >= 64) {
                // j==64 only at k==128: partner is other register, ascending
                int lo = min(key0, key1), hi = max(key0, key1);
                key0 = lo; key1 = hi;
            } else {
                int p0 = __shfl_xor(key0, j);
                int p1 = __shfl_xor(key1, j);
                bool lower = (lane & j) == 0;
                bool up0, up1;
                if (k >= 128)     { up0 = true;             up1 = true; }
                else if (k == 64) { up0 = true;             up1 = false; }
                else              { up0 = (lane & k) == 0;  up1 = up0; }
                key0 = (lower == up0) ? min(key0, p0) : max(key0, p0);
                key1 = (lower == up1) ? min(key1, p1) : max(key1, p1);
            }
        }
    }

    int found = hits < NS ? hits : NS;
    if (lane < found) {
        float4 P = s_hit[w][key0 & 0xFF];
        s_gx[w][lane] = P.x; s_gy[w][lane] = P.y; s_gz[w][lane] = P.z;
    }
    __syncthreads();

    // ---- pad unfilled slots with slot-0 point (ref: idx==N -> first, then -> 0) ----
    float p0x, p0y, p0z;
    if (found == 0) { p0x = xb[0]; p0y = xb[1]; p0z = xb[2]; }
    else            { p0x = s_gx[w][0]; p0y = s_gy[w][0]; p0z = s_gz[w][0]; }
    if (lane < NS && lane >= found) {
        s_gx[w][lane] = p0x; s_gy[w][lane] = p0y; s_gz[w][lane] = p0z;
    }
    __syncthreads();

    // ---- pairwise distance matrix (exact np op order, no fma contraction) ----
    #pragma unroll
    for (int t = 0; t < 16; ++t) {
        int e = t * 64 + lane;
        int di = e >> 5, dj = e & 31;
        float dx = __fsub_rn(s_gx[w][di], s_gx[w][dj]);
        float dy = __fsub_rn(s_gy[w][di], s_gy[w][dj]);
        float dz = __fsub_rn(s_gz[w][di], s_gz[w][dj]);
        s_dis[w][di][dj] =
            sqrtf(__fadd_rn(__fadd_rn(__fmul_rn(dx, dx), __fmul_rn(dy, dy)), __fmul_rn(dz, dz)));
    }
    __syncthreads();

    // ---- row sums in numpy pairwise-8 order; argmax first-occurrence tie-break ----
    {
        int i = lane & 31;
        float r[8];
        #pragma unroll
        for (int t = 0; t < 8; ++t) {
            r[t] = __fadd_rn(__fadd_rn(__fadd_rn(s_dis[w][i][t], s_dis[w][i][t + 8]),
                                        s_dis[w][i][t + 16]),
                             s_dis[w][i][t + 24]);
        }
        float mv = __fadd_rn(__fadd_rn(__fadd_rn(r[0], r[1]), __fadd_rn(r[2], r[3])),
                             __fadd_rn(__fadd_rn(r[4], r[5]), __fadd_rn(r[6], r[7])));
        int mi = i;
        #pragma unroll
        for (int off = 1; off < 64; off <<= 1) {
            float ov = __shfl_xor(mv, off);
            int oi = __shfl_xor(mi, off);
            if (ov > mv || (ov == mv && oi < mi)) { mv = ov; mi = oi; }
        }

        float tx = s_gx[w][mi], ty = s_gy[w][mi], tz = s_gz[w][mi];

        float ux = cy * tz - cz * ty, uy = cz * tx - cx * tz, uz = cx * ty - cy * tx;
        float vx = uy * cz - uz * cy, vy = uz * cx - ux * cz, vz = ux * cy - uy * cx;
        float vn = fmaxf(sqrtf(vx * vx + vy * vy + vz * vz), 1e-37f);
        float tnx = vx / vn, tny = vy / vn, tnz = vz / vn;

        float nr = sqrtf(cx * cx + cy * cy + cz * cz);
        float dn = nr + 1e-8f;
        float nnx = cx / dn, nny = cy / dn, nnz = cz / dn;

        int j = lane & 31;
        float gx = s_gx[w][j], gy = s_gy[w][j], gz = s_gz[w][j];

        float ax = cy * gz - cz * gy, ay = cz * gx - cx * gz, az = cx * gy - cy * gx;
        float px = ay * cz - az * cy, py = az * cx - ax * cz, pz = ax * cy - ay * cx;
        float pn = fmaxf(sqrtf(px * px + py * py + pz * pz), 1e-37f);
        px /= pn; py /= pn; pz /= pn;

        float qx = py * tnz - pz * tny;
        float qy = pz * tnx - px * tnz;
        float qz = px * tny - py * tnx;
        float sinv = qx * nnx + qy * nny + qz * nnz;

        float gr = sqrtf(gx * gx + gy * gy + gz * gz);

        const size_t rowstride = (size_t)MM * NS;
        const size_t obase = (((size_t)b * 33) * MM + m) * NS + j;
        if (lane < NS) out[obase + 32 * rowstride] = gr;

        float v[NS];
        #pragma unroll
        for (int ii = 0; ii < NS; ++ii) v[ii] = s_dis[w][ii][j];

        #pragma unroll
        for (int k = 2; k <= NS; k <<= 1) {
            #pragma unroll
            for (int jj = k >> 1; jj > 0; jj >>= 1) {
                #pragma unroll
                for (int ii = 0; ii < NS; ++ii) {
                    int ll = ii ^ jj;
                    if (ll > ii) {
                        bool up = ((ii & k) == 0);
                        float a = v[ii], c2 = v[ll];
                        bool sw = up ? (a > c2) : (a < c2);
                        if (sw) { v[ii] = c2; v[ll] = a; }
                    }
                }
            }
        }

        if (lane < NS) {
            #pragma unroll
            for (int ii = 0; ii < NS; ++ii)
                out[obase + (size_t)ii * rowstride] = v[ii] * sinv;
        }
    }
}

// ---------------- fallback: verified brute-force scan (round-4) ----------------
#define CHUNKS 4
__global__ __launch_bounds__(256) void qgr_kernel(
    const float* __restrict__ xyz,
    const float* __restrict__ nxyz,
    float* __restrict__ out) {

    __shared__ float s_gx[4][NS], s_gy[4][NS], s_gz[4][NS];
    __shared__ float s_dis[4][NS][NS + 1];

    const int lane = threadIdx.x & 63;
    const int w = threadIdx.x >> 6;
    const int q = blockIdx.x * 4 + w;
    const int b = q >> 11;
    const int m = q & (MM - 1);

    const float* xb = xyz + (size_t)b * NN * 3;
    const float* nq = nxyz + (size_t)q * 3;
    const float cx = nq[0], cy = nq[1], cz = nq[2];
    const unsigned long long lmask = (1ull << lane) - 1ull;

    int cnt = 0;
    for (int base = 0; base < NN; base += 64 * CHUNKS) {
        float X[CHUNKS], Y[CHUNKS], Z[CHUNKS];
        #pragma unroll
        for (int c = 0; c < CHUNKS; ++c) {
            const float* p = xb + (size_t)(base + c * 64 + lane) * 3;
            X[c] = p[0]; Y[c] = p[1]; Z[c] = p[2];
        }
        bool in[CHUNKS];
        #pragma unroll
        for (int c = 0; c < CHUNKS; ++c) {
            float dx = __fsub_rn(cx, X[c]);
            float dy = __fsub_rn(cy, Y[c]);
            float dz = __fsub_rn(cz, Z[c]);
            float d2 = __fadd_rn(__fadd_rn(__fmul_rn(dx, dx), __fmul_rn(dy, dy)),
                                 __fmul_rn(dz, dz));
            in[c] = d2 < R2;
        }
        #pragma unroll
        for (int c = 0; c < CHUNKS; ++c) {
            unsigned long long bal = __ballot(in[c]);
            if (bal) {
                int rank = __popcll(bal & lmask);
                int slot = cnt + rank;
                if (in[c] && slot < NS) {
                    s_gx[w][slot] = X[c]; s_gy[w][slot] = Y[c]; s_gz[w][slot] = Z[c];
                }
                cnt += __popcll(bal);
            }
        }
        if (cnt >= NS) break;
    }
    __syncthreads();

    int found = cnt < NS ? cnt : NS;
    float p0x, p0y, p0z;
    if (found == 0) { p0x = xb[0]; p0y = xb[1]; p0z = xb[2]; }
    else            { p0x = s_gx[w][0]; p0y = s_gy[w][0]; p0z = s_gz[w][0]; }
    if (lane < NS && lane >= found) {
        s_gx[w][lane] = p0x; s_gy[w][lane] = p0y; s_gz[w][lane] = p0z;
    }
    __syncthreads();

    #pragma unroll
    for (int t = 0; t < 16; ++t) {
        int e = t * 64 + lane;
        int di = e >> 5, dj = e & 31;
        float dx = __fsub_rn(s_gx[w][di], s_gx[w][dj]);
        float dy = __fsub_rn(s_gy[w][di], s_gy[w][dj]);
        float dz = __fsub_rn(s_gz[w][di], s_gz[w][dj]);
        s_dis[w][di][dj] =
            sqrtf(__fadd_rn(__fadd_rn(__fmul_rn(dx, dx), __fmul_rn(dy, dy)), __fmul_rn(dz, dz)));
    }
    __syncthreads();

    {
        int i = lane & 31;
        float r[8];
        #pragma unroll
        for (int t = 0; t < 8; ++t) {
            r[t] = __fadd_rn(__fadd_rn(__fadd_rn(s_dis[w][i][t], s_dis[w][i][t + 8]),
                                        s_dis[w][i][t + 16]),
                             s_dis[w][i][t + 24]);
        }
        float mv = __fadd_rn(__fadd_rn(__fadd_rn(r[0], r[1]), __fadd_rn(r[2], r[3])),
                             __fadd_rn(__fadd_rn(r[4], r[5]), __fadd_rn(r[6], r[7])));
        int mi = i;
        #pragma unroll
        for (int off = 1; off < 64; off <<= 1) {
            float ov = __shfl_xor(mv, off);
            int oi = __shfl_xor(mi, off);
            if (ov > mv || (ov == mv && oi < mi)) { mv = ov; mi = oi; }
        }
        float tx = s_gx[w][mi], ty = s_gy[w][mi], tz = s_gz[w][mi];
        float ux = cy * tz - cz * ty, uy = cz * tx - cx * tz, uz = cx * ty - cy * tx;
        float vx = uy * cz - uz * cy, vy = uz * cx - ux * cz, vz = ux * cy - uy * cx;
        float vn = fmaxf(sqrtf(vx * vx + vy * vy + vz * vz), 1e-37f);
        float tnx = vx / vn, tny = vy / vn, tnz = vz / vn;
        float nr = sqrtf(cx * cx + cy * cy + cz * cz);
        float dn = nr + 1e-8f;
        float nnx = cx / dn, nny = cy / dn, nnz = cz / dn;
        int j = lane & 31;
        float gx = s_gx[w][j], gy = s_gy[w][j], gz = s_gz[w][j];
        float ax = cy * gz - cz * gy, ay = cz * gx - cx * gz, az = cx * gy - cy * gx;
        float px = ay * cz - az * cy, py = az * cx - ax * cz, pz = ax * cy - ay * cx;
        float pn = fmaxf(sqrtf(px * px + py * py + pz * pz), 1e-37f);
        px /= pn; py /= pn; pz /= pn;
        float qx = py * tnz - pz * tny;
        float qy = pz * tnx - px * tnz;
        float qz = px * tny - py * tnx;
        float sinv = qx * nnx + qy * nny + qz * nnz;
        float gr = sqrtf(gx * gx + gy * gy + gz * gz);
        const size_t rowstride = (size_t)MM * NS;
        const size_t obase = (((size_t)b * 33) * MM + m) * NS + j;
        if (lane < NS) out[obase + 32 * rowstride] = gr;
        float v[NS];
        #pragma unroll
        for (int ii = 0; ii < NS; ++ii) v[ii] = s_dis[w][ii][j];
        #pragma unroll
        for (int k = 2; k <= NS; k <<= 1) {
            #pragma unroll
            for (int jj = k >> 1; jj > 0; jj >>= 1) {
                #pragma unroll
                for (int ii = 0; ii < NS; ++ii) {
                    int ll = ii ^ jj;
                    if (ll > ii) {
                        bool up = ((ii & k) == 0);
                        float a = v[ii], c2 = v[ll];
                        bool sw = up ? (a > c2) : (a < c2);
                        if (sw) { v[ii] = c2; v[ll] = a; }
                    }
                }
            }
        }
        if (lane < NS) {
            #pragma unroll
            for (int ii = 0; ii < NS; ++ii)
                out[obase + (size_t)ii * rowstride] = v[ii] * sinv;
        }
    }
}

extern "C" void kernel_launch(void* const* d_in, const int* in_sizes, int n_in,
                              void* d_out, int out_size, void* d_ws, size_t ws_size,
                              hipStream_t stream) {
    (void)in_sizes; (void)n_in; (void)out_size;
    const float* xyz = (const float*)d_in[0];
    const float* nxyz = (const float*)d_in[1];
    float* out = (float*)d_out;

    if (d_ws != nullptr && ws_size >= WS_NEED) {
        char* ws = (char*)d_ws;
        int* cnt = (int*)ws;
        int* off = (int*)(ws + WS_OFF_OFF);
        int* cur = (int*)(ws + WS_CUR_OFF);
        float4* pts = (float4*)(ws + WS_PTS_OFF);

        hipMemsetAsync(cnt, 0, 16 * 1024, stream);
        k_count<<<(BB * NN) / 256, 256, 0, stream>>>(xyz, cnt);
        k_scan<<<BB, 1024, 0, stream>>>(cnt, off, cur);
        k_scatter<<<(BB * NN) / 256, 256, 0, stream>>>(xyz, cur, pts);
        qgr_grid_kernel<<<(BB * MM) / 4, 256, 0, stream>>>(xyz, nxyz, off, pts, out);
    } else {
        qgr_kernel<<<(BB * MM) / 4, 256, 0, stream>>>(xyz, nxyz, out);
    }
}

// Round 6
// 114.759 us; speedup vs baseline: 1.1181x; 1.1181x over previous
//
#include <hip/hip_runtime.h>

// QueryAndGroupRRI: B=4, N=16384, M=2048, nsample=32, radius=0.1
// Inputs (float32): xyz (4,16384,3), new_xyz (4,2048,3)
// Output (float32): (4, 33, 2048, 32)  [dis_sort rows 0..31, grouped_r row 32]
//
// R6: 10^3 grid, z-merged 27->9 contiguous ranges, batched loads (append order
// across ranges is irrelevant: selection sorts by idx globally). Register-only
// dis matrix via wave shuffles (dis is bitwise-symmetric), SoA hit buffer,
// zero __syncthreads in query kernel. Single fused build kernel.

#define BB 4
#define NN 16384
#define MM 2048
#define NS 32
#define R2 0.01f
#define NCELL 1000
#define CPAD 1024
#define HCAP 128   // per-query hit cap (lambda~68, P(>128)~1e-13)

// ws layout: off int[4][1024] @0 (16KB) | pts float4[4][16384] @16KB (1MB)
#define WS_PTS_OFF (16 * 1024)
#define WS_NEED (WS_PTS_OFF + (size_t)BB * NN * 16)

__device__ __forceinline__ int cell_of(float x, float y, float z) {
    int ci = (int)(x * 10.0f); ci = ci < 0 ? 0 : (ci > 9 ? 9 : ci);
    int cj = (int)(y * 10.0f); cj = cj < 0 ? 0 : (cj > 9 ? 9 : cj);
    int ck = (int)(z * 10.0f); ck = ck < 0 ? 0 : (ck > 9 ? 9 : ck);
    return (ci * 10 + cj) * 10 + ck;
}

// ---- fused build: count -> scan -> scatter, one block per batch ----
__global__ __launch_bounds__(1024) void k_build(const float* __restrict__ xyz,
                                                int* __restrict__ off,
                                                float4* __restrict__ pts) {
    __shared__ int sc[1024];
    __shared__ int sa[1024];
    const int b = blockIdx.x, t = threadIdx.x;
    sc[t] = 0;
    __syncthreads();
    const float* xp = xyz + (size_t)b * NN * 3;
    float X[16], Y[16], Z[16]; int C[16];
    #pragma unroll
    for (int k = 0; k < 16; ++k) {
        int i = k * 1024 + t;
        const float* p = xp + (size_t)i * 3;
        X[k] = p[0]; Y[k] = p[1]; Z[k] = p[2];
        C[k] = cell_of(X[k], Y[k], Z[k]);
        atomicAdd(&sc[C[k]], 1);
    }
    __syncthreads();
    int v = sc[t];
    sa[t] = v;
    __syncthreads();
    for (int s = 1; s < 1024; s <<= 1) {
        int u = (t >= s) ? sa[t - s] : 0;
        __syncthreads();
        sa[t] += u;
        __syncthreads();
    }
    int excl = sa[t] - v;
    if (t < NCELL) off[b * CPAD + t] = excl;
    if (t == NCELL - 1) off[b * CPAD + NCELL] = sa[t];  // total = 16384
    __syncthreads();
    sc[t] = excl;  // cur
    __syncthreads();
    #pragma unroll
    for (int k = 0; k < 16; ++k) {
        int pos = atomicAdd(&sc[C[k]], 1);
        int i = k * 1024 + t;
        pts[(size_t)b * NN + pos] = make_float4(X[k], Y[k], Z[k], __int_as_float(i));
    }
}

__global__ __launch_bounds__(256) void qgr_grid_kernel(
    const float* __restrict__ xyz,
    const float* __restrict__ nxyz,
    const int* __restrict__ offi,
    const float4* __restrict__ pts,
    float* __restrict__ out) {

    // SoA hit buffers: stride-4B -> bank-conflict-free (2-way is free on wave64)
    __shared__ float s_hx[4][HCAP], s_hy[4][HCAP], s_hz[4][HCAP];
    __shared__ int   s_hidx[4][HCAP];

    const int lane = threadIdx.x & 63;
    const int w = threadIdx.x >> 6;
    const int q = blockIdx.x * 4 + w;
    const int b = q >> 11;
    const int m = q & (MM - 1);

    const float* xb = xyz + (size_t)b * NN * 3;
    const float* nq = nxyz + (size_t)q * 3;
    const float cx = nq[0], cy = nq[1], cz = nq[2];
    const unsigned long long lmask = (1ull << lane) - 1ull;

    const int* offb = offi + b * CPAD;
    const float4* ptsb = pts + (size_t)b * NN;

    // ---- 27 neighbor cells = up to 9 z-contiguous ranges ----
    int ci0 = (int)(cx * 10.0f); ci0 = ci0 < 0 ? 0 : (ci0 > 9 ? 9 : ci0);
    int cj0 = (int)(cy * 10.0f); cj0 = cj0 < 0 ? 0 : (cj0 > 9 ? 9 : cj0);
    int ck0 = (int)(cz * 10.0f); ck0 = ck0 < 0 ? 0 : (ck0 > 9 ? 9 : ck0);
    int zlo = ck0 > 0 ? ck0 - 1 : 0;
    int zhi = ck0 < 9 ? ck0 + 1 : 9;

    int rs[9], rl[9];
    #pragma unroll
    for (int r = 0; r < 9; ++r) { rs[r] = 0; rl[r] = 0; }
    int nr = 0;
    #pragma unroll
    for (int di = -1; di <= 1; ++di) {
        int ii = ci0 + di; if ((unsigned)ii > 9u) continue;
        #pragma unroll
        for (int dj = -1; dj <= 1; ++dj) {
            int jj = cj0 + dj; if ((unsigned)jj > 9u) continue;
            int base2 = (ii * 10 + jj) * 10;
            int s0 = offb[base2 + zlo];
            int e0 = offb[base2 + zhi + 1];
            int len = e0 - s0;
            if (len > 0) { rs[nr] = s0; rl[nr] = len; ++nr; }
        }
    }

    // ---- batched first-round loads for all 9 ranges (one latency exposure) ----
    float4 P[9];
    #pragma unroll
    for (int r = 0; r < 9; ++r) {
        int a = (lane < rl[r]) ? (rs[r] + lane) : 0;
        P[r] = ptsb[a];
    }

    int hits = 0;
    #pragma unroll
    for (int r = 0; r < 9; ++r) {
        float dx = __fsub_rn(cx, P[r].x);
        float dy = __fsub_rn(cy, P[r].y);
        float dz = __fsub_rn(cz, P[r].z);
        float d2 = __fadd_rn(__fadd_rn(__fmul_rn(dx, dx), __fmul_rn(dy, dy)),
                             __fmul_rn(dz, dz));
        bool hit = (lane < rl[r]) && (d2 < R2);
        unsigned long long bal = __ballot(hit);
        if (bal) {
            int rank = __popcll(bal & lmask);
            int slot = hits + rank;
            if (hit && slot < HCAP) {
                s_hx[w][slot] = P[r].x; s_hy[w][slot] = P[r].y;
                s_hz[w][slot] = P[r].z; s_hidx[w][slot] = __float_as_int(P[r].w);
            }
            hits += __popcll(bal);
        }
    }
    // rare leftovers: ranges longer than 64
    for (int r = 0; r < nr; ++r) {
        for (int t0 = 64; t0 < rl[r]; t0 += 64) {   // wave-uniform
            int t = t0 + lane;
            bool act = t < rl[r];
            float4 Q = ptsb[rs[r] + (act ? t : 0)];
            float dx = __fsub_rn(cx, Q.x);
            float dy = __fsub_rn(cy, Q.y);
            float dz = __fsub_rn(cz, Q.z);
            float d2 = __fadd_rn(__fadd_rn(__fmul_rn(dx, dx), __fmul_rn(dy, dy)),
                                 __fmul_rn(dz, dz));
            bool hit = act && (d2 < R2);
            unsigned long long bal = __ballot(hit);
            if (bal) {
                int rank = __popcll(bal & lmask);
                int slot = hits + rank;
                if (hit && slot < HCAP) {
                    s_hx[w][slot] = Q.x; s_hy[w][slot] = Q.y;
                    s_hz[w][slot] = Q.z; s_hidx[w][slot] = __float_as_int(Q.w);
                }
                hits += __popcll(bal);
            }
        }
    }

    // ---- select 32 smallest indices: 128-elem register bitonic (verified R5) ----
    int cap = hits < HCAP ? hits : HCAP;
    int key0 = (lane < cap)      ? ((s_hidx[w][lane] << 8) | lane)            : 0x7fffffff;
    int key1 = (64 + lane < cap) ? ((s_hidx[w][64 + lane] << 8) | (64 + lane)) : 0x7fffffff;

    #pragma unroll
    for (int k = 2; k <= 128; k <<= 1) {
        #pragma unroll
        for (int j = k >> 1; j > 0; j >>= 1) {
            if (j >= 64) {
                int lo = min(key0, key1), hi = max(key0, key1);
                key0 = lo; key1 = hi;
            } else {
                int p0 = __shfl_xor(key0, j);
                int p1 = __shfl_xor(key1, j);
                bool lower = (lane & j) == 0;
                bool up0, up1;
                if (k >= 128)     { up0 = true;             up1 = true; }
                else if (k == 64) { up0 = true;             up1 = false; }
                else              { up0 = (lane & k) == 0;  up1 = up0; }
                key0 = (lower == up0) ? min(key0, p0) : max(key0, p0);
                key1 = (lower == up1) ? min(key1, p1) : max(key1, p1);
            }
        }
    }

    const int found = hits < NS ? hits : NS;
    const int j = lane & 31;
    // both wave halves take column j (mirrors verified i=lane&31 layout)
    int skey = __shfl(key0, j);
    float hx = 0.f, hy = 0.f, hz = 0.f;
    if (j < found) {
        int s = skey & 0xFF;
        hx = s_hx[w][s]; hy = s_hy[w][s]; hz = s_hz[w][s];
    }
    float p0x, p0y, p0z;
    if (found == 0) { p0x = xb[0]; p0y = xb[1]; p0z = xb[2]; }
    else { p0x = __shfl(hx, 0); p0y = __shfl(hy, 0); p0z = __shfl(hz, 0); }
    if (j >= found) { hx = p0x; hy = p0y; hz = p0z; }

    // ---- dis column j in registers (bitwise-symmetric => row j), np op order ----
    float v[NS];
    #pragma unroll
    for (int ii = 0; ii < NS; ++ii) {
        float bx = __shfl(hx, ii), by = __shfl(hy, ii), bz = __shfl(hz, ii);
        float dx = __fsub_rn(bx, hx);
        float dy = __fsub_rn(by, hy);
        float dz = __fsub_rn(bz, hz);
        v[ii] = sqrtf(__fadd_rn(__fadd_rn(__fmul_rn(dx, dx), __fmul_rn(dy, dy)),
                                __fmul_rn(dz, dz)));
    }

    // row-j sum in numpy pairwise-8 order; argmax first-occurrence tie-break
    float r8[8];
    #pragma unroll
    for (int t = 0; t < 8; ++t) {
        r8[t] = __fadd_rn(__fadd_rn(__fadd_rn(v[t], v[t + 8]), v[t + 16]), v[t + 24]);
    }
    float mv = __fadd_rn(__fadd_rn(__fadd_rn(r8[0], r8[1]), __fadd_rn(r8[2], r8[3])),
                         __fadd_rn(__fadd_rn(r8[4], r8[5]), __fadd_rn(r8[6], r8[7])));
    int mi = j;
    #pragma unroll
    for (int off = 1; off < 64; off <<= 1) {
        float ov = __shfl_xor(mv, off);
        int oi = __shfl_xor(mi, off);
        if (ov > mv || (ov == mv && oi < mi)) { mv = ov; mi = oi; }
    }

    float tx = __shfl(hx, mi), ty = __shfl(hy, mi), tz = __shfl(hz, mi);

    float ux = cy * tz - cz * ty, uy = cz * tx - cx * tz, uz = cx * ty - cy * tx;
    float vx = uy * cz - uz * cy, vy = uz * cx - ux * cz, vz = ux * cy - uy * cx;
    float vn = fmaxf(sqrtf(vx * vx + vy * vy + vz * vz), 1e-37f);
    float tnx = vx / vn, tny = vy / vn, tnz = vz / vn;

    float nrm = sqrtf(cx * cx + cy * cy + cz * cz);
    float dn = nrm + 1e-8f;
    float nnx = cx / dn, nny = cy / dn, nnz = cz / dn;

    float ax = cy * hz - cz * hy, ay = cz * hx - cx * hz, az = cx * hy - cy * hx;
    float px = ay * cz - az * cy, py = az * cx - ax * cz, pz = ax * cy - ay * cx;
    float pn = fmaxf(sqrtf(px * px + py * py + pz * pz), 1e-37f);
    px /= pn; py /= pn; pz /= pn;

    float qx = py * tnz - pz * tny;
    float qy = pz * tnx - px * tnz;
    float qz = px * tny - py * tnx;
    float sinv = qx * nnx + qy * nny + qz * nnz;

    float gr = sqrtf(hx * hx + hy * hy + hz * hz);

    const size_t rowstride = (size_t)MM * NS;
    const size_t obase = (((size_t)b * 33) * MM + m) * NS + j;
    if (lane < NS) out[obase + 32 * rowstride] = gr;

    // bitonic sort ascending (verified network)
    #pragma unroll
    for (int k = 2; k <= NS; k <<= 1) {
        #pragma unroll
        for (int jj = k >> 1; jj > 0; jj >>= 1) {
            #pragma unroll
            for (int ii = 0; ii < NS; ++ii) {
                int ll = ii ^ jj;
                if (ll > ii) {
                    bool up = ((ii & k) == 0);
                    float a = v[ii], c2 = v[ll];
                    bool sw = up ? (a > c2) : (a < c2);
                    if (sw) { v[ii] = c2; v[ll] = a; }
                }
            }
        }
    }

    if (lane < NS) {
        #pragma unroll
        for (int ii = 0; ii < NS; ++ii)
            out[obase + (size_t)ii * rowstride] = v[ii] * sinv;
    }
}

// ---------------- fallback: verified brute-force scan (round-4) ----------------
#define CHUNKS 4
__global__ __launch_bounds__(256) void qgr_kernel(
    const float* __restrict__ xyz,
    const float* __restrict__ nxyz,
    float* __restrict__ out) {

    __shared__ float s_gx[4][NS], s_gy[4][NS], s_gz[4][NS];
    __shared__ float s_dis[4][NS][NS + 1];

    const int lane = threadIdx.x & 63;
    const int w = threadIdx.x >> 6;
    const int q = blockIdx.x * 4 + w;
    const int b = q >> 11;
    const int m = q & (MM - 1);

    const float* xb = xyz + (size_t)b * NN * 3;
    const float* nq = nxyz + (size_t)q * 3;
    const float cx = nq[0], cy = nq[1], cz = nq[2];
    const unsigned long long lmask = (1ull << lane) - 1ull;

    int cnt = 0;
    for (int base = 0; base < NN; base += 64 * CHUNKS) {
        float X[CHUNKS], Y[CHUNKS], Z[CHUNKS];
        #pragma unroll
        for (int c = 0; c < CHUNKS; ++c) {
            const float* p = xb + (size_t)(base + c * 64 + lane) * 3;
            X[c] = p[0]; Y[c] = p[1]; Z[c] = p[2];
        }
        bool in[CHUNKS];
        #pragma unroll
        for (int c = 0; c < CHUNKS; ++c) {
            float dx = __fsub_rn(cx, X[c]);
            float dy = __fsub_rn(cy, Y[c]);
            float dz = __fsub_rn(cz, Z[c]);
            float d2 = __fadd_rn(__fadd_rn(__fmul_rn(dx, dx), __fmul_rn(dy, dy)),
                                 __fmul_rn(dz, dz));
            in[c] = d2 < R2;
        }
        #pragma unroll
        for (int c = 0; c < CHUNKS; ++c) {
            unsigned long long bal = __ballot(in[c]);
            if (bal) {
                int rank = __popcll(bal & lmask);
                int slot = cnt + rank;
                if (in[c] && slot < NS) {
                    s_gx[w][slot] = X[c]; s_gy[w][slot] = Y[c]; s_gz[w][slot] = Z[c];
                }
                cnt += __popcll(bal);
            }
        }
        if (cnt >= NS) break;
    }
    __syncthreads();

    int found = cnt < NS ? cnt : NS;
    float p0x, p0y, p0z;
    if (found == 0) { p0x = xb[0]; p0y = xb[1]; p0z = xb[2]; }
    else            { p0x = s_gx[w][0]; p0y = s_gy[w][0]; p0z = s_gz[w][0]; }
    if (lane < NS && lane >= found) {
        s_gx[w][lane] = p0x; s_gy[w][lane] = p0y; s_gz[w][lane] = p0z;
    }
    __syncthreads();

    #pragma unroll
    for (int t = 0; t < 16; ++t) {
        int e = t * 64 + lane;
        int di = e >> 5, dj = e & 31;
        float dx = __fsub_rn(s_gx[w][di], s_gx[w][dj]);
        float dy = __fsub_rn(s_gy[w][di], s_gy[w][dj]);
        float dz = __fsub_rn(s_gz[w][di], s_gz[w][dj]);
        s_dis[w][di][dj] =
            sqrtf(__fadd_rn(__fadd_rn(__fmul_rn(dx, dx), __fmul_rn(dy, dy)), __fmul_rn(dz, dz)));
    }
    __syncthreads();

    {
        int i = lane & 31;
        float r[8];
        #pragma unroll
        for (int t = 0; t < 8; ++t) {
            r[t] = __fadd_rn(__fadd_rn(__fadd_rn(s_dis[w][i][t], s_dis[w][i][t + 8]),
                                        s_dis[w][i][t + 16]),
                             s_dis[w][i][t + 24]);
        }
        float mv = __fadd_rn(__fadd_rn(__fadd_rn(r[0], r[1]), __fadd_rn(r[2], r[3])),
                             __fadd_rn(__fadd_rn(r[4], r[5]), __fadd_rn(r[6], r[7])));
        int mi = i;
        #pragma unroll
        for (int off = 1; off < 64; off <<= 1) {
            float ov = __shfl_xor(mv, off);
            int oi = __shfl_xor(mi, off);
            if (ov > mv || (ov == mv && oi < mi)) { mv = ov; mi = oi; }
        }
        float tx = s_gx[w][mi], ty = s_gy[w][mi], tz = s_gz[w][mi];
        float ux = cy * tz - cz * ty, uy = cz * tx - cx * tz, uz = cx * ty - cy * tx;
        float vx = uy * cz - uz * cy, vy = uz * cx - ux * cz, vz = ux * cy - uy * cx;
        float vn = fmaxf(sqrtf(vx * vx + vy * vy + vz * vz), 1e-37f);
        float tnx = vx / vn, tny = vy / vn, tnz = vz / vn;
        float nr = sqrtf(cx * cx + cy * cy + cz * cz);
        float dn = nr + 1e-8f;
        float nnx = cx / dn, nny = cy / dn, nnz = cz / dn;
        int j = lane & 31;
        float gx = s_gx[w][j], gy = s_gy[w][j], gz = s_gz[w][j];
        float ax = cy * gz - cz * gy, ay = cz * gx - cx * gz, az = cx * gy - cy * gx;
        float px = ay * cz - az * cy, py = az * cx - ax * cz, pz = ax * cy - ay * cx;
        float pn = fmaxf(sqrtf(px * px + py * py + pz * pz), 1e-37f);
        px /= pn; py /= pn; pz /= pn;
        float qx = py * tnz - pz * tny;
        float qy = pz * tnx - px * tnz;
        float qz = px * tny - py * tnx;
        float sinv = qx * nnx + qy * nny + qz * nnz;
        float gr = sqrtf(gx * gx + gy * gy + gz * gz);
        const size_t rowstride = (size_t)MM * NS;
        const size_t obase = (((size_t)b * 33) * MM + m) * NS + j;
        if (lane < NS) out[obase + 32 * rowstride] = gr;
        float v[NS];
        #pragma unroll
        for (int ii = 0; ii < NS; ++ii) v[ii] = s_dis[w][ii][j];
        #pragma unroll
        for (int k = 2; k <= NS; k <<= 1) {
            #pragma unroll
            for (int jj = k >> 1; jj > 0; jj >>= 1) {
                #pragma unroll
                for (int ii = 0; ii < NS; ++ii) {
                    int ll = ii ^ jj;
                    if (ll > ii) {
                        bool up = ((ii & k) == 0);
                        float a = v[ii], c2 = v[ll];
                        bool sw = up ? (a > c2) : (a < c2);
                        if (sw) { v[ii] = c2; v[ll] = a; }
                    }
                }
            }
        }
        if (lane < NS) {
            #pragma unroll
            for (int ii = 0; ii < NS; ++ii)
                out[obase + (size_t)ii * rowstride] = v[ii] * sinv;
        }
    }
}

extern "C" void kernel_launch(void* const* d_in, const int* in_sizes, int n_in,
                              void* d_out, int out_size, void* d_ws, size_t ws_size,
                              hipStream_t stream) {
    (void)in_sizes; (void)n_in; (void)out_size;
    const float* xyz = (const float*)d_in[0];
    const float* nxyz = (const float*)d_in[1];
    float* out = (float*)d_out;

    if (d_ws != nullptr && ws_size >= WS_NEED) {
        char* ws = (char*)d_ws;
        int* off = (int*)ws;
        float4* pts = (float4*)(ws + WS_PTS_OFF);
        k_build<<<BB, 1024, 0, stream>>>(xyz, off, pts);
        qgr_grid_kernel<<<(BB * MM) / 4, 256, 0, stream>>>(xyz, nxyz, off, pts, out);
    } else {
        qgr_kernel<<<(BB * MM) / 4, 256, 0, stream>>>(xyz, nxyz, out);
    }
}

// Round 7
// 105.300 us; speedup vs baseline: 1.2185x; 1.0898x over previous
//
#include <hip/hip_runtime.h>

// QueryAndGroupRRI: B=4, N=16384, M=2048, nsample=32, radius=0.1
// Inputs (float32): xyz (4,16384,3), new_xyz (4,2048,3)
// Output (float32): (4, 33, 2048, 32)  [dis_sort rows 0..31, grouped_r row 32]
//
// R7: two queries per wave (lanes 0-31 -> q0, 32-63 -> q1) halves phase-2 work;
// 128-elem selection bitonic in 4 regs x 32 lanes; k_build scan via wave
// shuffles (3 barriers instead of 20). Build + query = 2 dispatches.

#define BB 4
#define NN 16384
#define MM 2048
#define NS 32
#define R2 0.01f
#define NCELL 1000
#define CPAD 1024
#define HCAP 128   // per-query hit cap (lambda~68; verified sufficient R5/R6)

// ws layout: off int[4][1024] @0 (16KB) | pts float4[4][16384] @16KB (1MB)
#define WS_PTS_OFF (16 * 1024)
#define WS_NEED (WS_PTS_OFF + (size_t)BB * NN * 16)

__device__ __forceinline__ int cell_of(float x, float y, float z) {
    int ci = (int)(x * 10.0f); ci = ci < 0 ? 0 : (ci > 9 ? 9 : ci);
    int cj = (int)(y * 10.0f); cj = cj < 0 ? 0 : (cj > 9 ? 9 : cj);
    int ck = (int)(z * 10.0f); ck = ck < 0 ? 0 : (ck > 9 ? 9 : ck);
    return (ci * 10 + cj) * 10 + ck;
}

// ---- fused build: count -> wave-scan -> scatter (3 barriers) ----
__global__ __launch_bounds__(1024) void k_build(const float* __restrict__ xyz,
                                                int* __restrict__ off,
                                                float4* __restrict__ pts) {
    __shared__ int sc[1024];
    __shared__ int wsum[16];
    const int b = blockIdx.x, t = threadIdx.x;
    const int lane = t & 63, wid = t >> 6;
    sc[t] = 0;
    __syncthreads();
    const float* xp = xyz + (size_t)b * NN * 3;
    float X[16], Y[16], Z[16]; int C[16];
    #pragma unroll
    for (int k = 0; k < 16; ++k) {
        int i = k * 1024 + t;
        const float* p = xp + (size_t)i * 3;
        X[k] = p[0]; Y[k] = p[1]; Z[k] = p[2];
        C[k] = cell_of(X[k], Y[k], Z[k]);
        atomicAdd(&sc[C[k]], 1);
    }
    __syncthreads();
    int v = sc[t];
    // wave-level inclusive scan
    int x = v;
    #pragma unroll
    for (int o = 1; o < 64; o <<= 1) {
        int u = __shfl_up(x, o);
        if (lane >= o) x += u;
    }
    if (lane == 63) wsum[wid] = x;
    __syncthreads();
    int pre = 0;
    #pragma unroll
    for (int i2 = 0; i2 < 16; ++i2) pre += (i2 < wid) ? wsum[i2] : 0;
    int incl = x + pre;
    int excl = incl - v;
    if (t < NCELL) off[b * CPAD + t] = excl;
    if (t == 1023) off[b * CPAD + NCELL] = incl;  // total = 16384
    __syncthreads();
    sc[t] = excl;  // cur
    __syncthreads();
    #pragma unroll
    for (int k = 0; k < 16; ++k) {
        int pos = atomicAdd(&sc[C[k]], 1);
        int i = k * 1024 + t;
        pts[(size_t)b * NN + pos] = make_float4(X[k], Y[k], Z[k], __int_as_float(i));
    }
}

__global__ __launch_bounds__(256) void qgr_grid_kernel(
    const float* __restrict__ xyz,
    const float* __restrict__ nxyz,
    const int* __restrict__ offi,
    const float4* __restrict__ pts,
    float* __restrict__ out) {

    // per-wave, per-query SoA hit buffers (stride-4B -> conflict-free)
    __shared__ float s_hx[4][2][HCAP], s_hy[4][2][HCAP], s_hz[4][2][HCAP];
    __shared__ int   s_hidx[4][2][HCAP];

    const int lane = threadIdx.x & 63;
    const int w = threadIdx.x >> 6;
    const int sub = lane & 31;
    const int half = lane >> 5;
    const int q0 = blockIdx.x * 8 + w * 2;     // even; q0,q0+1 share batch b
    const int b = q0 >> 11;

    const float* xb = xyz + (size_t)b * NN * 3;
    const float* nq = nxyz + (size_t)q0 * 3;
    const float cx0 = nq[0], cy0 = nq[1], cz0 = nq[2];
    const float cx1 = nq[3], cy1 = nq[4], cz1 = nq[5];
    const unsigned long long lmask = (1ull << lane) - 1ull;

    const int* offb = offi + b * CPAD;
    const float4* ptsb = pts + (size_t)b * NN;

    // ---- phase 1: full-wave scan, one query at a time ----
    int hits01[2];
    for (int tq = 0; tq < 2; ++tq) {
        const float ccx = tq ? cx1 : cx0;
        const float ccy = tq ? cy1 : cy0;
        const float ccz = tq ? cz1 : cz0;

        int ci0 = (int)(ccx * 10.0f); ci0 = ci0 < 0 ? 0 : (ci0 > 9 ? 9 : ci0);
        int cj0 = (int)(ccy * 10.0f); cj0 = cj0 < 0 ? 0 : (cj0 > 9 ? 9 : cj0);
        int ck0 = (int)(ccz * 10.0f); ck0 = ck0 < 0 ? 0 : (ck0 > 9 ? 9 : ck0);
        int zlo = ck0 > 0 ? ck0 - 1 : 0;
        int zhi = ck0 < 9 ? ck0 + 1 : 9;

        int rs[9], rl[9];
        #pragma unroll
        for (int r = 0; r < 9; ++r) { rs[r] = 0; rl[r] = 0; }
        int nr = 0;
        #pragma unroll
        for (int di = -1; di <= 1; ++di) {
            int ii = ci0 + di; if ((unsigned)ii > 9u) continue;
            #pragma unroll
            for (int dj = -1; dj <= 1; ++dj) {
                int jj = cj0 + dj; if ((unsigned)jj > 9u) continue;
                int base2 = (ii * 10 + jj) * 10;
                int s0 = offb[base2 + zlo];
                int e0 = offb[base2 + zhi + 1];
                int len = e0 - s0;
                if (len > 0) { rs[nr] = s0; rl[nr] = len; ++nr; }
            }
        }

        float4 P[9];
        #pragma unroll
        for (int r = 0; r < 9; ++r) {
            int a = (lane < rl[r]) ? (rs[r] + lane) : 0;
            P[r] = ptsb[a];
        }

        int hits = 0;
        #pragma unroll
        for (int r = 0; r < 9; ++r) {
            float dx = __fsub_rn(ccx, P[r].x);
            float dy = __fsub_rn(ccy, P[r].y);
            float dz = __fsub_rn(ccz, P[r].z);
            float d2 = __fadd_rn(__fadd_rn(__fmul_rn(dx, dx), __fmul_rn(dy, dy)),
                                 __fmul_rn(dz, dz));
            bool hit = (lane < rl[r]) && (d2 < R2);
            unsigned long long bal = __ballot(hit);
            if (bal) {
                int rank = __popcll(bal & lmask);
                int slot = hits + rank;
                if (hit && slot < HCAP) {
                    s_hx[w][tq][slot] = P[r].x; s_hy[w][tq][slot] = P[r].y;
                    s_hz[w][tq][slot] = P[r].z; s_hidx[w][tq][slot] = __float_as_int(P[r].w);
                }
                hits += __popcll(bal);
            }
        }
        for (int r = 0; r < nr; ++r) {           // rare: ranges > 64
            for (int t0 = 64; t0 < rl[r]; t0 += 64) {
                int t = t0 + lane;
                bool act = t < rl[r];
                float4 Q = ptsb[rs[r] + (act ? t : 0)];
                float dx = __fsub_rn(ccx, Q.x);
                float dy = __fsub_rn(ccy, Q.y);
                float dz = __fsub_rn(ccz, Q.z);
                float d2 = __fadd_rn(__fadd_rn(__fmul_rn(dx, dx), __fmul_rn(dy, dy)),
                                     __fmul_rn(dz, dz));
                bool hit = act && (d2 < R2);
                unsigned long long bal = __ballot(hit);
                if (bal) {
                    int rank = __popcll(bal & lmask);
                    int slot = hits + rank;
                    if (hit && slot < HCAP) {
                        s_hx[w][tq][slot] = Q.x; s_hy[w][tq][slot] = Q.y;
                        s_hz[w][tq][slot] = Q.z; s_hidx[w][tq][slot] = __float_as_int(Q.w);
                    }
                    hits += __popcll(bal);
                }
            }
        }
        hits01[tq] = hits;
    }

    // ---- phase 2: each 32-lane half handles its own query ----
    const int hits = half ? hits01[1] : hits01[0];
    const int cap = hits < HCAP ? hits : HCAP;
    const float ccx = half ? cx1 : cx0;
    const float ccy = half ? cy1 : cy0;
    const float ccz = half ? cz1 : cz0;

    // 128-elem bitonic sort in 4 regs x 32 lanes; element e = r*32 + sub.
    // canonical network: for k=2..128, j=k/2..1; dir(e,k) = ((e&k)==0).
    int key[4];
    #pragma unroll
    for (int r = 0; r < 4; ++r) {
        int e = r * 32 + sub;
        key[r] = (e < cap) ? ((s_hidx[w][half][e] << 8) | e) : 0x7fffffff;
    }

    // k = 2,4,8,16: cross-lane only, dir = (sub & k)==0 (same for all regs)
    #pragma unroll
    for (int k = 2; k <= 16; k <<= 1) {
        #pragma unroll
        for (int j = k >> 1; j > 0; j >>= 1) {
            bool lower = (sub & j) == 0;
            bool asc = (sub & k) == 0;
            bool keepmin = (lower == asc);
            #pragma unroll
            for (int r = 0; r < 4; ++r) {
                int p = __shfl_xor(key[r], j);
                key[r] = keepmin ? min(key[r], p) : max(key[r], p);
            }
        }
    }
    // k = 32: dir_r = ((r&1)==0); j = 16..1 cross-lane
    #pragma unroll
    for (int j = 16; j > 0; j >>= 1) {
        bool lower = (sub & j) == 0;
        #pragma unroll
        for (int r = 0; r < 4; ++r) {
            int p = __shfl_xor(key[r], j);
            bool asc = (r & 1) == 0;
            key[r] = (lower == asc) ? min(key[r], p) : max(key[r], p);
        }
    }
    // k = 64: j=32 in-register (pairs r0r1 asc, r2r3 desc), then j=16..1, dir_r=((r&2)==0)
    {
        int t0 = min(key[0], key[1]); key[1] = max(key[0], key[1]); key[0] = t0;
        int t2 = max(key[2], key[3]); key[3] = min(key[2], key[3]); key[2] = t2;
    }
    #pragma unroll
    for (int j = 16; j > 0; j >>= 1) {
        bool lower = (sub & j) == 0;
        #pragma unroll
        for (int r = 0; r < 4; ++r) {
            int p = __shfl_xor(key[r], j);
            bool asc = (r & 2) == 0;
            key[r] = (lower == asc) ? min(key[r], p) : max(key[r], p);
        }
    }
    // k = 128: j=64, j=32 in-register (all asc), then j=16..1 cross-lane asc
    {
        int t0 = min(key[0], key[2]); key[2] = max(key[0], key[2]); key[0] = t0;
        int t1 = min(key[1], key[3]); key[3] = max(key[1], key[3]); key[1] = t1;
        t0 = min(key[0], key[1]); key[1] = max(key[0], key[1]); key[0] = t0;
        t1 = min(key[2], key[3]); key[3] = max(key[2], key[3]); key[2] = t1;
    }
    #pragma unroll
    for (int j = 16; j > 0; j >>= 1) {
        bool lower = (sub & j) == 0;
        #pragma unroll
        for (int r = 0; r < 4; ++r) {
            int p = __shfl_xor(key[r], j);
            key[r] = lower ? min(key[r], p) : max(key[r], p);
        }
    }

    // smallest 32 = elements 0..31 = key[0] across sub ascending
    const int found = hits < NS ? hits : NS;
    const int hbase = half << 5;
    float hx = 0.f, hy = 0.f, hz = 0.f;
    if (sub < found) {
        int s = key[0] & 0xFF;
        hx = s_hx[w][half][s]; hy = s_hy[w][half][s]; hz = s_hz[w][half][s];
    }
    float p0x, p0y, p0z;
    if (found == 0) { p0x = xb[0]; p0y = xb[1]; p0z = xb[2]; }
    else { p0x = __shfl(hx, hbase); p0y = __shfl(hy, hbase); p0z = __shfl(hz, hbase); }
    if (sub >= found) { hx = p0x; hy = p0y; hz = p0z; }

    // dis column j=sub in registers (bitwise-symmetric), exact np op order
    float v[NS];
    #pragma unroll
    for (int ii = 0; ii < NS; ++ii) {
        float bx = __shfl(hx, hbase + ii);
        float by = __shfl(hy, hbase + ii);
        float bz = __shfl(hz, hbase + ii);
        float dx = __fsub_rn(bx, hx);
        float dy = __fsub_rn(by, hy);
        float dz = __fsub_rn(bz, hz);
        v[ii] = sqrtf(__fadd_rn(__fadd_rn(__fmul_rn(dx, dx), __fmul_rn(dy, dy)),
                                __fmul_rn(dz, dz)));
    }

    // row-sub sum in numpy pairwise-8 order; half-local argmax, first-occurrence
    float r8[8];
    #pragma unroll
    for (int t = 0; t < 8; ++t) {
        r8[t] = __fadd_rn(__fadd_rn(__fadd_rn(v[t], v[t + 8]), v[t + 16]), v[t + 24]);
    }
    float mv = __fadd_rn(__fadd_rn(__fadd_rn(r8[0], r8[1]), __fadd_rn(r8[2], r8[3])),
                         __fadd_rn(__fadd_rn(r8[4], r8[5]), __fadd_rn(r8[6], r8[7])));
    int mi = sub;
    #pragma unroll
    for (int off = 1; off < 32; off <<= 1) {
        float ov = __shfl_xor(mv, off);
        int oi = __shfl_xor(mi, off);
        if (ov > mv || (ov == mv && oi < mi)) { mv = ov; mi = oi; }
    }

    float tx = __shfl(hx, hbase + mi), ty = __shfl(hy, hbase + mi), tz = __shfl(hz, hbase + mi);

    float ux = ccy * tz - ccz * ty, uy = ccz * tx - ccx * tz, uz = ccx * ty - ccy * tx;
    float vx = uy * ccz - uz * ccy, vy = uz * ccx - ux * ccz, vz = ux * ccy - uy * ccx;
    float vn = fmaxf(sqrtf(vx * vx + vy * vy + vz * vz), 1e-37f);
    float tnx = vx / vn, tny = vy / vn, tnz = vz / vn;

    float nrm = sqrtf(ccx * ccx + ccy * ccy + ccz * ccz);
    float dn = nrm + 1e-8f;
    float nnx = ccx / dn, nny = ccy / dn, nnz = ccz / dn;

    float ax = ccy * hz - ccz * hy, ay = ccz * hx - ccx * hz, az = ccx * hy - ccy * hx;
    float px = ay * ccz - az * ccy, py = az * ccx - ax * ccz, pz = ax * ccy - ay * ccx;
    float pn = fmaxf(sqrtf(px * px + py * py + pz * pz), 1e-37f);
    px /= pn; py /= pn; pz /= pn;

    float qx = py * tnz - pz * tny;
    float qy = pz * tnx - px * tnz;
    float qz = px * tny - py * tnx;
    float sinv = qx * nnx + qy * nny + qz * nnz;

    float gr = sqrtf(hx * hx + hy * hy + hz * hz);

    const int m_h = (q0 + half) & (MM - 1);
    const size_t rowstride = (size_t)MM * NS;
    const size_t obase = (((size_t)b * 33) * MM + m_h) * NS + sub;
    out[obase + 32 * rowstride] = gr;

    // per-lane bitonic sort ascending (verified network)
    #pragma unroll
    for (int k = 2; k <= NS; k <<= 1) {
        #pragma unroll
        for (int jj = k >> 1; jj > 0; jj >>= 1) {
            #pragma unroll
            for (int ii = 0; ii < NS; ++ii) {
                int ll = ii ^ jj;
                if (ll > ii) {
                    bool up = ((ii & k) == 0);
                    float a = v[ii], c2 = v[ll];
                    bool sw = up ? (a > c2) : (a < c2);
                    if (sw) { v[ii] = c2; v[ll] = a; }
                }
            }
        }
    }

    #pragma unroll
    for (int ii = 0; ii < NS; ++ii)
        out[obase + (size_t)ii * rowstride] = v[ii] * sinv;
}

// ---------------- fallback: verified brute-force scan (round-4) ----------------
#define CHUNKS 4
__global__ __launch_bounds__(256) void qgr_kernel(
    const float* __restrict__ xyz,
    const float* __restrict__ nxyz,
    float* __restrict__ out) {

    __shared__ float s_gx[4][NS], s_gy[4][NS], s_gz[4][NS];
    __shared__ float s_dis[4][NS][NS + 1];

    const int lane = threadIdx.x & 63;
    const int w = threadIdx.x >> 6;
    const int q = blockIdx.x * 4 + w;
    const int b = q >> 11;
    const int m = q & (MM - 1);

    const float* xb = xyz + (size_t)b * NN * 3;
    const float* nq = nxyz + (size_t)q * 3;
    const float cx = nq[0], cy = nq[1], cz = nq[2];
    const unsigned long long lmask = (1ull << lane) - 1ull;

    int cnt = 0;
    for (int base = 0; base < NN; base += 64 * CHUNKS) {
        float X[CHUNKS], Y[CHUNKS], Z[CHUNKS];
        #pragma unroll
        for (int c = 0; c < CHUNKS; ++c) {
            const float* p = xb + (size_t)(base + c * 64 + lane) * 3;
            X[c] = p[0]; Y[c] = p[1]; Z[c] = p[2];
        }
        bool in[CHUNKS];
        #pragma unroll
        for (int c = 0; c < CHUNKS; ++c) {
            float dx = __fsub_rn(cx, X[c]);
            float dy = __fsub_rn(cy, Y[c]);
            float dz = __fsub_rn(cz, Z[c]);
            float d2 = __fadd_rn(__fadd_rn(__fmul_rn(dx, dx), __fmul_rn(dy, dy)),
                                 __fmul_rn(dz, dz));
            in[c] = d2 < R2;
        }
        #pragma unroll
        for (int c = 0; c < CHUNKS; ++c) {
            unsigned long long bal = __ballot(in[c]);
            if (bal) {
                int rank = __popcll(bal & lmask);
                int slot = cnt + rank;
                if (in[c] && slot < NS) {
                    s_gx[w][slot] = X[c]; s_gy[w][slot] = Y[c]; s_gz[w][slot] = Z[c];
                }
                cnt += __popcll(bal);
            }
        }
        if (cnt >= NS) break;
    }
    __syncthreads();

    int found = cnt < NS ? cnt : NS;
    float p0x, p0y, p0z;
    if (found == 0) { p0x = xb[0]; p0y = xb[1]; p0z = xb[2]; }
    else            { p0x = s_gx[w][0]; p0y = s_gy[w][0]; p0z = s_gz[w][0]; }
    if (lane < NS && lane >= found) {
        s_gx[w][lane] = p0x; s_gy[w][lane] = p0y; s_gz[w][lane] = p0z;
    }
    __syncthreads();

    #pragma unroll
    for (int t = 0; t < 16; ++t) {
        int e = t * 64 + lane;
        int di = e >> 5, dj = e & 31;
        float dx = __fsub_rn(s_gx[w][di], s_gx[w][dj]);
        float dy = __fsub_rn(s_gy[w][di], s_gy[w][dj]);
        float dz = __fsub_rn(s_gz[w][di], s_gz[w][dj]);
        s_dis[w][di][dj] =
            sqrtf(__fadd_rn(__fadd_rn(__fmul_rn(dx, dx), __fmul_rn(dy, dy)), __fmul_rn(dz, dz)));
    }
    __syncthreads();

    {
        int i = lane & 31;
        float r[8];
        #pragma unroll
        for (int t = 0; t < 8; ++t) {
            r[t] = __fadd_rn(__fadd_rn(__fadd_rn(s_dis[w][i][t], s_dis[w][i][t + 8]),
                                        s_dis[w][i][t + 16]),
                             s_dis[w][i][t + 24]);
        }
        float mv = __fadd_rn(__fadd_rn(__fadd_rn(r[0], r[1]), __fadd_rn(r[2], r[3])),
                             __fadd_rn(__fadd_rn(r[4], r[5]), __fadd_rn(r[6], r[7])));
        int mi = i;
        #pragma unroll
        for (int off = 1; off < 64; off <<= 1) {
            float ov = __shfl_xor(mv, off);
            int oi = __shfl_xor(mi, off);
            if (ov > mv || (ov == mv && oi < mi)) { mv = ov; mi = oi; }
        }
        float tx = s_gx[w][mi], ty = s_gy[w][mi], tz = s_gz[w][mi];
        float ux = cy * tz - cz * ty, uy = cz * tx - cx * tz, uz = cx * ty - cy * tx;
        float vx = uy * cz - uz * cy, vy = uz * cx - ux * cz, vz = ux * cy - uy * cx;
        float vn = fmaxf(sqrtf(vx * vx + vy * vy + vz * vz), 1e-37f);
        float tnx = vx / vn, tny = vy / vn, tnz = vz / vn;
        float nr = sqrtf(cx * cx + cy * cy + cz * cz);
        float dn = nr + 1e-8f;
        float nnx = cx / dn, nny = cy / dn, nnz = cz / dn;
        int j = lane & 31;
        float gx = s_gx[w][j], gy = s_gy[w][j], gz = s_gz[w][j];
        float ax = cy * gz - cz * gy, ay = cz * gx - cx * gz, az = cx * gy - cy * gx;
        float px = ay * cz - az * cy, py = az * cx - ax * cz, pz = ax * cy - ay * cx;
        float pn = fmaxf(sqrtf(px * px + py * py + pz * pz), 1e-37f);
        px /= pn; py /= pn; pz /= pn;
        float qx = py * tnz - pz * tny;
        float qy = pz * tnx - px * tnz;
        float qz = px * tny - py * tnx;
        float sinv = qx * nnx + qy * nny + qz * nnz;
        float gr = sqrtf(gx * gx + gy * gy + gz * gz);
        const size_t rowstride = (size_t)MM * NS;
        const size_t obase = (((size_t)b * 33) * MM + m) * NS + j;
        if (lane < NS) out[obase + 32 * rowstride] = gr;
        float v[NS];
        #pragma unroll
        for (int ii = 0; ii < NS; ++ii) v[ii] = s_dis[w][ii][j];
        #pragma unroll
        for (int k = 2; k <= NS; k <<= 1) {
            #pragma unroll
            for (int jj = k >> 1; jj > 0; jj >>= 1) {
                #pragma unroll
                for (int ii = 0; ii < NS; ++ii) {
                    int ll = ii ^ jj;
                    if (ll > ii) {
                        bool up = ((ii & k) == 0);
                        float a = v[ii], c2 = v[ll];
                        bool sw = up ? (a > c2) : (a < c2);
                        if (sw) { v[ii] = c2; v[ll] = a; }
                    }
                }
            }
        }
        if (lane < NS) {
            #pragma unroll
            for (int ii = 0; ii < NS; ++ii)
                out[obase + (size_t)ii * rowstride] = v[ii] * sinv;
        }
    }
}

extern "C" void kernel_launch(void* const* d_in, const int* in_sizes, int n_in,
                              void* d_out, int out_size, void* d_ws, size_t ws_size,
                              hipStream_t stream) {
    (void)in_sizes; (void)n_in; (void)out_size;
    const float* xyz = (const float*)d_in[0];
    const float* nxyz = (const float*)d_in[1];
    float* out = (float*)d_out;

    if (d_ws != nullptr && ws_size >= WS_NEED) {
        char* ws = (char*)d_ws;
        int* off = (int*)ws;
        float4* pts = (float4*)(ws + WS_PTS_OFF);
        k_build<<<BB, 1024, 0, stream>>>(xyz, off, pts);
        // 8192 queries, 2 per wave, 4 waves/block -> 1024 blocks
        qgr_grid_kernel<<<(BB * MM) / 8, 256, 0, stream>>>(xyz, nxyz, off, pts, out);
    } else {
        qgr_kernel<<<(BB * MM) / 4, 256, 0, stream>>>(xyz, nxyz, out);
    }
}

// Round 8
// 103.399 us; speedup vs baseline: 1.2409x; 1.0184x over previous
//
#include <hip/hip_runtime.h>

// QueryAndGroupRRI: B=4, N=16384, M=2048, nsample=32, radius=0.1
// Inputs (float32): xyz (4,16384,3), new_xyz (4,2048,3)
// Output (float32): (4, 33, 2048, 32)  [dis_sort rows 0..31, grouped_r row 32]
//
// R8: 10x10x20 grid (z-window +-2 => -17% tests); float4 LDS hit buffer
// (ds_write_b128 append, ds_read_b128 broadcasts for dis/tip); per-lane sort
// switched to Batcher odd-even mergesort (191 CE, min/max). Two queries per
// wave (lanes 0-31 -> q0, 32-63 -> q1). Build + query = 2 dispatches.

#define BB 4
#define NN 16384
#define MM 2048
#define NS 32
#define R2 0.01f
#define GZ 20          // z slabs
#define NCELL 2000     // 10*10*20
#define CPAD 2048
#define HCAP 128       // per-query hit cap (lambda~68, +7sigma safe)

// ws layout: off int[4][2048] @0 (32KB) | pts float4[4][16384] @32KB (1MB)
#define WS_PTS_OFF (32 * 1024)
#define WS_NEED (WS_PTS_OFF + (size_t)BB * NN * 16)

__device__ __forceinline__ int cell_of(float x, float y, float z) {
    int ci = (int)(x * 10.0f); ci = ci < 0 ? 0 : (ci > 9 ? 9 : ci);
    int cj = (int)(y * 10.0f); cj = cj < 0 ? 0 : (cj > 9 ? 9 : cj);
    int ck = (int)(z * 20.0f); ck = ck < 0 ? 0 : (ck > 19 ? 19 : ck);
    return (ci * 10 + cj) * GZ + ck;
}

// ---- fused build: count -> wave-scan (2 cells/thread) -> scatter ----
__global__ __launch_bounds__(1024) void k_build(const float* __restrict__ xyz,
                                                int* __restrict__ off,
                                                float4* __restrict__ pts) {
    __shared__ int sc[CPAD];
    __shared__ int wsum[16];
    const int b = blockIdx.x, t = threadIdx.x;
    const int lane = t & 63, wid = t >> 6;
    sc[t] = 0; sc[1024 + t] = 0;
    __syncthreads();
    const float* xp = xyz + (size_t)b * NN * 3;
    float X[16], Y[16], Z[16]; int C[16];
    #pragma unroll
    for (int k = 0; k < 16; ++k) {
        int i = k * 1024 + t;
        const float* p = xp + (size_t)i * 3;
        X[k] = p[0]; Y[k] = p[1]; Z[k] = p[2];
        C[k] = cell_of(X[k], Y[k], Z[k]);
        atomicAdd(&sc[C[k]], 1);
    }
    __syncthreads();
    int v0 = sc[2 * t], v1 = sc[2 * t + 1];
    int s = v0 + v1;
    int x = s;
    #pragma unroll
    for (int o = 1; o < 64; o <<= 1) {
        int u = __shfl_up(x, o);
        if (lane >= o) x += u;
    }
    if (lane == 63) wsum[wid] = x;
    __syncthreads();
    int pre = 0;
    #pragma unroll
    for (int i2 = 0; i2 < 16; ++i2) pre += (i2 < wid) ? wsum[i2] : 0;
    int incl = x + pre;
    int excl = incl - s;
    off[b * CPAD + 2 * t] = excl;
    off[b * CPAD + 2 * t + 1] = excl + v0;
    __syncthreads();
    sc[2 * t] = excl; sc[2 * t + 1] = excl + v0;  // cur
    __syncthreads();
    #pragma unroll
    for (int k = 0; k < 16; ++k) {
        int pos = atomicAdd(&sc[C[k]], 1);
        int i = k * 1024 + t;
        pts[(size_t)b * NN + pos] = make_float4(X[k], Y[k], Z[k], __int_as_float(i));
    }
}

__global__ __launch_bounds__(256) void qgr_grid_kernel(
    const float* __restrict__ xyz,
    const float* __restrict__ nxyz,
    const int* __restrict__ offi,
    const float4* __restrict__ pts,
    float* __restrict__ out) {

    __shared__ float4 s_hit[4][2][HCAP];   // 16 KB: hit (x,y,z,idx-bits)
    __shared__ float4 s_sel[4][2][NS];     // 4 KB: selected 32, slot order

    const int lane = threadIdx.x & 63;
    const int w = threadIdx.x >> 6;
    const int sub = lane & 31;
    const int half = lane >> 5;
    const int q0 = blockIdx.x * 8 + w * 2;     // even; q0,q0+1 share batch b
    const int b = q0 >> 11;

    const float* xb = xyz + (size_t)b * NN * 3;
    const float* nq = nxyz + (size_t)q0 * 3;
    const float cx0 = nq[0], cy0 = nq[1], cz0 = nq[2];
    const float cx1 = nq[3], cy1 = nq[4], cz1 = nq[5];
    const unsigned long long lmask = (1ull << lane) - 1ull;

    const int* offb = offi + b * CPAD;
    const float4* ptsb = pts + (size_t)b * NN;

    // ---- phase 1: full-wave scan, one query at a time ----
    int hits01[2];
    for (int tq = 0; tq < 2; ++tq) {
        const float ccx = tq ? cx1 : cx0;
        const float ccy = tq ? cy1 : cy0;
        const float ccz = tq ? cz1 : cz0;

        int ci0 = (int)(ccx * 10.0f); ci0 = ci0 < 0 ? 0 : (ci0 > 9 ? 9 : ci0);
        int cj0 = (int)(ccy * 10.0f); cj0 = cj0 < 0 ? 0 : (cj0 > 9 ? 9 : cj0);
        int ck0 = (int)(ccz * 20.0f); ck0 = ck0 < 0 ? 0 : (ck0 > 19 ? 19 : ck0);
        int zlo = ck0 > 2 ? ck0 - 2 : 0;
        int zhi = ck0 < 17 ? ck0 + 2 : 19;

        int rs[9], rl[9];
        #pragma unroll
        for (int r = 0; r < 9; ++r) { rs[r] = 0; rl[r] = 0; }
        int nr = 0;
        #pragma unroll
        for (int di = -1; di <= 1; ++di) {
            int ii = ci0 + di; if ((unsigned)ii > 9u) continue;
            #pragma unroll
            for (int dj = -1; dj <= 1; ++dj) {
                int jj = cj0 + dj; if ((unsigned)jj > 9u) continue;
                int base2 = (ii * 10 + jj) * GZ;
                int s0 = offb[base2 + zlo];
                int e0 = offb[base2 + zhi + 1];
                int len = e0 - s0;
                if (len > 0) { rs[nr] = s0; rl[nr] = len; ++nr; }
            }
        }

        float4 P[9];
        #pragma unroll
        for (int r = 0; r < 9; ++r) {
            int a = (lane < rl[r]) ? (rs[r] + lane) : 0;
            P[r] = ptsb[a];
        }

        int hits = 0;
        #pragma unroll
        for (int r = 0; r < 9; ++r) {
            float dx = __fsub_rn(ccx, P[r].x);
            float dy = __fsub_rn(ccy, P[r].y);
            float dz = __fsub_rn(ccz, P[r].z);
            float d2 = __fadd_rn(__fadd_rn(__fmul_rn(dx, dx), __fmul_rn(dy, dy)),
                                 __fmul_rn(dz, dz));
            bool hit = (lane < rl[r]) && (d2 < R2);
            unsigned long long bal = __ballot(hit);
            if (bal) {
                int rank = __popcll(bal & lmask);
                int slot = hits + rank;
                if (hit && slot < HCAP) s_hit[w][tq][slot] = P[r];
                hits += __popcll(bal);
            }
        }
        for (int r = 0; r < nr; ++r) {           // rare: ranges > 64
            for (int t0 = 64; t0 < rl[r]; t0 += 64) {
                int t = t0 + lane;
                bool act = t < rl[r];
                float4 Q = ptsb[rs[r] + (act ? t : 0)];
                float dx = __fsub_rn(ccx, Q.x);
                float dy = __fsub_rn(ccy, Q.y);
                float dz = __fsub_rn(ccz, Q.z);
                float d2 = __fadd_rn(__fadd_rn(__fmul_rn(dx, dx), __fmul_rn(dy, dy)),
                                     __fmul_rn(dz, dz));
                bool hit = act && (d2 < R2);
                unsigned long long bal = __ballot(hit);
                if (bal) {
                    int rank = __popcll(bal & lmask);
                    int slot = hits + rank;
                    if (hit && slot < HCAP) s_hit[w][tq][slot] = Q;
                    hits += __popcll(bal);
                }
            }
        }
        hits01[tq] = hits;
    }

    // ---- phase 2: each 32-lane half handles its own query ----
    const int hits = half ? hits01[1] : hits01[0];
    const int cap = hits < HCAP ? hits : HCAP;
    const float ccx = half ? cx1 : cx0;
    const float ccy = half ? cy1 : cy0;
    const float ccz = half ? cz1 : cz0;

    // 128-elem bitonic in 4 regs x 32 lanes (verified R7); key = idx<<8 | slot
    int key[4];
    #pragma unroll
    for (int r = 0; r < 4; ++r) {
        int e = r * 32 + sub;
        int idx_e = __float_as_int(s_hit[w][half][e].w);
        key[r] = (e < cap) ? ((idx_e << 8) | e) : 0x7fffffff;
    }

    #pragma unroll
    for (int k = 2; k <= 16; k <<= 1) {
        #pragma unroll
        for (int j = k >> 1; j > 0; j >>= 1) {
            bool lower = (sub & j) == 0;
            bool asc = (sub & k) == 0;
            bool keepmin = (lower == asc);
            #pragma unroll
            for (int r = 0; r < 4; ++r) {
                int p = __shfl_xor(key[r], j);
                key[r] = keepmin ? min(key[r], p) : max(key[r], p);
            }
        }
    }
    #pragma unroll
    for (int j = 16; j > 0; j >>= 1) {
        bool lower = (sub & j) == 0;
        #pragma unroll
        for (int r = 0; r < 4; ++r) {
            int p = __shfl_xor(key[r], j);
            bool asc = (r & 1) == 0;
            key[r] = (lower == asc) ? min(key[r], p) : max(key[r], p);
        }
    }
    {
        int t0 = min(key[0], key[1]); key[1] = max(key[0], key[1]); key[0] = t0;
        int t2 = max(key[2], key[3]); key[3] = min(key[2], key[3]); key[2] = t2;
    }
    #pragma unroll
    for (int j = 16; j > 0; j >>= 1) {
        bool lower = (sub & j) == 0;
        #pragma unroll
        for (int r = 0; r < 4; ++r) {
            int p = __shfl_xor(key[r], j);
            bool asc = (r & 2) == 0;
            key[r] = (lower == asc) ? min(key[r], p) : max(key[r], p);
        }
    }
    {
        int t0 = min(key[0], key[2]); key[2] = max(key[0], key[2]); key[0] = t0;
        int t1 = min(key[1], key[3]); key[3] = max(key[1], key[3]); key[1] = t1;
        t0 = min(key[0], key[1]); key[1] = max(key[0], key[1]); key[0] = t0;
        t1 = min(key[2], key[3]); key[3] = max(key[2], key[3]); key[2] = t1;
    }
    #pragma unroll
    for (int j = 16; j > 0; j >>= 1) {
        bool lower = (sub & j) == 0;
        #pragma unroll
        for (int r = 0; r < 4; ++r) {
            int p = __shfl_xor(key[r], j);
            key[r] = lower ? min(key[r], p) : max(key[r], p);
        }
    }

    // fetch selected points (smallest 32 indices, ascending), pad with slot 0
    const int found = hits < NS ? hits : NS;
    const int hbase = half << 5;
    float4 sel = make_float4(0.f, 0.f, 0.f, 0.f);
    if (sub < found) sel = s_hit[w][half][key[0] & 0xFF];
    float p0x, p0y, p0z;
    if (found == 0) { p0x = xb[0]; p0y = xb[1]; p0z = xb[2]; }
    else {
        p0x = __shfl(sel.x, hbase); p0y = __shfl(sel.y, hbase); p0z = __shfl(sel.z, hbase);
    }
    if (sub >= found) { sel.x = p0x; sel.y = p0y; sel.z = p0z; }
    const float hx = sel.x, hy = sel.y, hz = sel.z;

    // stage selected pts for broadcast reads
    s_sel[w][half][sub] = sel;

    // dis column j=sub via ds_read_b128 broadcasts (exact np op order)
    float v[NS];
    #pragma unroll
    for (int ii = 0; ii < NS; ++ii) {
        float4 B = s_sel[w][half][ii];
        float dx = __fsub_rn(B.x, hx);
        float dy = __fsub_rn(B.y, hy);
        float dz = __fsub_rn(B.z, hz);
        v[ii] = sqrtf(__fadd_rn(__fadd_rn(__fmul_rn(dx, dx), __fmul_rn(dy, dy)),
                                __fmul_rn(dz, dz)));
    }

    // row-sub sum in numpy pairwise-8 order; half-local argmax, first-occurrence
    float r8[8];
    #pragma unroll
    for (int t = 0; t < 8; ++t) {
        r8[t] = __fadd_rn(__fadd_rn(__fadd_rn(v[t], v[t + 8]), v[t + 16]), v[t + 24]);
    }
    float mv = __fadd_rn(__fadd_rn(__fadd_rn(r8[0], r8[1]), __fadd_rn(r8[2], r8[3])),
                         __fadd_rn(__fadd_rn(r8[4], r8[5]), __fadd_rn(r8[6], r8[7])));
    int mi = sub;
    #pragma unroll
    for (int off = 1; off < 32; off <<= 1) {
        float ov = __shfl_xor(mv, off);
        int oi = __shfl_xor(mi, off);
        if (ov > mv || (ov == mv && oi < mi)) { mv = ov; mi = oi; }
    }

    float4 T = s_sel[w][half][mi];
    const float tx = T.x, ty = T.y, tz = T.z;

    float ux = ccy * tz - ccz * ty, uy = ccz * tx - ccx * tz, uz = ccx * ty - ccy * tx;
    float vx = uy * ccz - uz * ccy, vy = uz * ccx - ux * ccz, vz = ux * ccy - uy * ccx;
    float vn = fmaxf(sqrtf(vx * vx + vy * vy + vz * vz), 1e-37f);
    float tnx = vx / vn, tny = vy / vn, tnz = vz / vn;

    float nrm = sqrtf(ccx * ccx + ccy * ccy + ccz * ccz);
    float dn = nrm + 1e-8f;
    float nnx = ccx / dn, nny = ccy / dn, nnz = ccz / dn;

    float ax = ccy * hz - ccz * hy, ay = ccz * hx - ccx * hz, az = ccx * hy - ccy * hx;
    float px = ay * ccz - az * ccy, py = az * ccx - ax * ccz, pz = ax * ccy - ay * ccx;
    float pn = fmaxf(sqrtf(px * px + py * py + pz * pz), 1e-37f);
    px /= pn; py /= pn; pz /= pn;

    float qx = py * tnz - pz * tny;
    float qy = pz * tnx - px * tnz;
    float qz = px * tny - py * tnx;
    float sinv = qx * nnx + qy * nny + qz * nnz;

    float gr = sqrtf(hx * hx + hy * hy + hz * hz);

    const int m_h = (q0 + half) & (MM - 1);
    const size_t rowstride = (size_t)MM * NS;
    const size_t obase = (((size_t)b * 33) * MM + m_h) * NS + sub;
    out[obase + 32 * rowstride] = gr;

    // per-lane ascending sort: Batcher odd-even mergesort, 191 min/max CEs
    #pragma unroll
    for (int p = 1; p < NS; p <<= 1) {
        #pragma unroll
        for (int k = p; k >= 1; k >>= 1) {
            #pragma unroll
            for (int j = k & (p - 1); j + k < NS; j += 2 * k) {
                #pragma unroll
                for (int i = 0; i < k; ++i) {
                    if (i + j + k < NS) {
                        int x = i + j, y = i + j + k;
                        if ((x / (2 * p)) == (y / (2 * p))) {
                            float lo = fminf(v[x], v[y]);
                            v[y] = fmaxf(v[x], v[y]);
                            v[x] = lo;
                        }
                    }
                }
            }
        }
    }

    #pragma unroll
    for (int ii = 0; ii < NS; ++ii)
        out[obase + (size_t)ii * rowstride] = v[ii] * sinv;
}

// ---------------- fallback: verified brute-force scan (round-4) ----------------
#define CHUNKS 4
__global__ __launch_bounds__(256) void qgr_kernel(
    const float* __restrict__ xyz,
    const float* __restrict__ nxyz,
    float* __restrict__ out) {

    __shared__ float s_gx[4][NS], s_gy[4][NS], s_gz[4][NS];
    __shared__ float s_dis[4][NS][NS + 1];

    const int lane = threadIdx.x & 63;
    const int w = threadIdx.x >> 6;
    const int q = blockIdx.x * 4 + w;
    const int b = q >> 11;
    const int m = q & (MM - 1);

    const float* xb = xyz + (size_t)b * NN * 3;
    const float* nq = nxyz + (size_t)q * 3;
    const float cx = nq[0], cy = nq[1], cz = nq[2];
    const unsigned long long lmask = (1ull << lane) - 1ull;

    int cnt = 0;
    for (int base = 0; base < NN; base += 64 * CHUNKS) {
        float X[CHUNKS], Y[CHUNKS], Z[CHUNKS];
        #pragma unroll
        for (int c = 0; c < CHUNKS; ++c) {
            const float* p = xb + (size_t)(base + c * 64 + lane) * 3;
            X[c] = p[0]; Y[c] = p[1]; Z[c] = p[2];
        }
        bool in[CHUNKS];
        #pragma unroll
        for (int c = 0; c < CHUNKS; ++c) {
            float dx = __fsub_rn(cx, X[c]);
            float dy = __fsub_rn(cy, Y[c]);
            float dz = __fsub_rn(cz, Z[c]);
            float d2 = __fadd_rn(__fadd_rn(__fmul_rn(dx, dx), __fmul_rn(dy, dy)),
                                 __fmul_rn(dz, dz));
            in[c] = d2 < R2;
        }
        #pragma unroll
        for (int c = 0; c < CHUNKS; ++c) {
            unsigned long long bal = __ballot(in[c]);
            if (bal) {
                int rank = __popcll(bal & lmask);
                int slot = cnt + rank;
                if (in[c] && slot < NS) {
                    s_gx[w][slot] = X[c]; s_gy[w][slot] = Y[c]; s_gz[w][slot] = Z[c];
                }
                cnt += __popcll(bal);
            }
        }
        if (cnt >= NS) break;
    }
    __syncthreads();

    int found = cnt < NS ? cnt : NS;
    float p0x, p0y, p0z;
    if (found == 0) { p0x = xb[0]; p0y = xb[1]; p0z = xb[2]; }
    else            { p0x = s_gx[w][0]; p0y = s_gy[w][0]; p0z = s_gz[w][0]; }
    if (lane < NS && lane >= found) {
        s_gx[w][lane] = p0x; s_gy[w][lane] = p0y; s_gz[w][lane] = p0z;
    }
    __syncthreads();

    #pragma unroll
    for (int t = 0; t < 16; ++t) {
        int e = t * 64 + lane;
        int di = e >> 5, dj = e & 31;
        float dx = __fsub_rn(s_gx[w][di], s_gx[w][dj]);
        float dy = __fsub_rn(s_gy[w][di], s_gy[w][dj]);
        float dz = __fsub_rn(s_gz[w][di], s_gz[w][dj]);
        s_dis[w][di][dj] =
            sqrtf(__fadd_rn(__fadd_rn(__fmul_rn(dx, dx), __fmul_rn(dy, dy)), __fmul_rn(dz, dz)));
    }
    __syncthreads();

    {
        int i = lane & 31;
        float r[8];
        #pragma unroll
        for (int t = 0; t < 8; ++t) {
            r[t] = __fadd_rn(__fadd_rn(__fadd_rn(s_dis[w][i][t], s_dis[w][i][t + 8]),
                                        s_dis[w][i][t + 16]),
                             s_dis[w][i][t + 24]);
        }
        float mv = __fadd_rn(__fadd_rn(__fadd_rn(r[0], r[1]), __fadd_rn(r[2], r[3])),
                             __fadd_rn(__fadd_rn(r[4], r[5]), __fadd_rn(r[6], r[7])));
        int mi = i;
        #pragma unroll
        for (int off = 1; off < 64; off <<= 1) {
            float ov = __shfl_xor(mv, off);
            int oi = __shfl_xor(mi, off);
            if (ov > mv || (ov == mv && oi < mi)) { mv = ov; mi = oi; }
        }
        float tx = s_gx[w][mi], ty = s_gy[w][mi], tz = s_gz[w][mi];
        float ux = cy * tz - cz * ty, uy = cz * tx - cx * tz, uz = cx * ty - cy * tx;
        float vx = uy * cz - uz * cy, vy = uz * cx - ux * cz, vz = ux * cy - uy * cx;
        float vn = fmaxf(sqrtf(vx * vx + vy * vy + vz * vz), 1e-37f);
        float tnx = vx / vn, tny = vy / vn, tnz = vz / vn;
        float nr = sqrtf(cx * cx + cy * cy + cz * cz);
        float dn = nr + 1e-8f;
        float nnx = cx / dn, nny = cy / dn, nnz = cz / dn;
        int j = lane & 31;
        float gx = s_gx[w][j], gy = s_gy[w][j], gz = s_gz[w][j];
        float ax = cy * gz - cz * gy, ay = cz * gx - cx * gz, az = cx * gy - cy * gx;
        float px = ay * cz - az * cy, py = az * cx - ax * cz, pz = ax * cy - ay * cx;
        float pn = fmaxf(sqrtf(px * px + py * py + pz * pz), 1e-37f);
        px /= pn; py /= pn; pz /= pn;
        float qx = py * tnz - pz * tny;
        float qy = pz * tnx - px * tnz;
        float qz = px * tny - py * tnx;
        float sinv = qx * nnx + qy * nny + qz * nnz;
        float gr = sqrtf(gx * gx + gy * gy + gz * gz);
        const size_t rowstride = (size_t)MM * NS;
        const size_t obase = (((size_t)b * 33) * MM + m) * NS + j;
        if (lane < NS) out[obase + 32 * rowstride] = gr;
        float v[NS];
        #pragma unroll
        for (int ii = 0; ii < NS; ++ii) v[ii] = s_dis[w][ii][j];
        #pragma unroll
        for (int k = 2; k <= NS; k <<= 1) {
            #pragma unroll
            for (int jj = k >> 1; jj > 0; jj >>= 1) {
                #pragma unroll
                for (int ii = 0; ii < NS; ++ii) {
                    int ll = ii ^ jj;
                    if (ll > ii) {
                        bool up = ((ii & k) == 0);
                        float a = v[ii], c2 = v[ll];
                        bool sw = up ? (a > c2) : (a < c2);
                        if (sw) { v[ii] = c2; v[ll] = a; }
                    }
                }
            }
        }
        if (lane < NS) {
            #pragma unroll
            for (int ii = 0; ii < NS; ++ii)
                out[obase + (size_t)ii * rowstride] = v[ii] * sinv;
        }
    }
}

extern "C" void kernel_launch(void* const* d_in, const int* in_sizes, int n_in,
                              void* d_out, int out_size, void* d_ws, size_t ws_size,
                              hipStream_t stream) {
    (void)in_sizes; (void)n_in; (void)out_size;
    const float* xyz = (const float*)d_in[0];
    const float* nxyz = (const float*)d_in[1];
    float* out = (float*)d_out;

    if (d_ws != nullptr && ws_size >= WS_NEED) {
        char* ws = (char*)d_ws;
        int* off = (int*)ws;
        float4* pts = (float4*)(ws + WS_PTS_OFF);
        k_build<<<BB, 1024, 0, stream>>>(xyz, off, pts);
        // 8192 queries, 2 per wave, 4 waves/block -> 1024 blocks
        qgr_grid_kernel<<<(BB * MM) / 8, 256, 0, stream>>>(xyz, nxyz, off, pts, out);
    } else {
        qgr_kernel<<<(BB * MM) / 4, 256, 0, stream>>>(xyz, nxyz, out);
    }
}

// Round 9
// 98.764 us; speedup vs baseline: 1.2992x; 1.0469x over previous
//
#include <hip/hip_runtime.h>

// QueryAndGroupRRI: B=4, N=16384, M=2048, nsample=32, radius=0.1
// Inputs (float32): xyz (4,16384,3), new_xyz (4,2048,3)
// Output (float32): (4, 33, 2048, 32)  [dis_sort rows 0..31, grouped_r row 32]
//
// R9: wide 3-kernel grid build (count/scan/scatter over 256 blocks; global
// atomics in L2) replaces the 4-block LDS-atomic k_build (~20 us on 4 CUs).
// Query kernel identical to verified R8: 10x10x20 grid, float4 LDS hits,
// 128-elem selection bitonic, Batcher 32-sort, 2 queries/wave.

#define BB 4
#define NN 16384
#define MM 2048
#define NS 32
#define R2 0.01f
#define GZ 20          // z slabs
#define NCELL 2000     // 10*10*20
#define CPAD 2048
#define HCAP 128       // per-query hit cap (lambda~68, +7sigma safe)

// ws layout: off int[4][2048] @0 | cur @32KB | cnt @64KB | pts float4 @96KB
#define WS_CUR_OFF (32 * 1024)
#define WS_CNT_OFF (64 * 1024)
#define WS_PTS_OFF (96 * 1024)
#define WS_NEED (WS_PTS_OFF + (size_t)BB * NN * 16)

__device__ __forceinline__ int cell_of(float x, float y, float z) {
    int ci = (int)(x * 10.0f); ci = ci < 0 ? 0 : (ci > 9 ? 9 : ci);
    int cj = (int)(y * 10.0f); cj = cj < 0 ? 0 : (cj > 9 ? 9 : cj);
    int ck = (int)(z * 20.0f); ck = ck < 0 ? 0 : (ck > 19 ? 19 : ck);
    return (ci * 10 + cj) * GZ + ck;
}

__global__ __launch_bounds__(256) void k_count(const float* __restrict__ xyz,
                                               int* __restrict__ cnt) {
    int i = blockIdx.x * 256 + threadIdx.x;   // 0..65535
    int b = i >> 14;
    const float* p = xyz + (size_t)i * 3;
    atomicAdd(&cnt[b * CPAD + cell_of(p[0], p[1], p[2])], 1);
}

// 4 blocks (one per batch) x 1024 threads; 2 cells/thread; wave-shuffle scan
__global__ __launch_bounds__(1024) void k_scan(const int* __restrict__ cnt,
                                               int* __restrict__ off,
                                               int* __restrict__ cur) {
    __shared__ int wsum[16];
    const int b = blockIdx.x, t = threadIdx.x;
    const int lane = t & 63, wid = t >> 6;
    int v0 = cnt[b * CPAD + 2 * t];
    int v1 = cnt[b * CPAD + 2 * t + 1];
    int s = v0 + v1;
    int x = s;
    #pragma unroll
    for (int o = 1; o < 64; o <<= 1) {
        int u = __shfl_up(x, o);
        if (lane >= o) x += u;
    }
    if (lane == 63) wsum[wid] = x;
    __syncthreads();
    int pre = 0;
    #pragma unroll
    for (int i2 = 0; i2 < 16; ++i2) pre += (i2 < wid) ? wsum[i2] : 0;
    int incl = x + pre;
    int excl = incl - s;
    off[b * CPAD + 2 * t] = excl;
    off[b * CPAD + 2 * t + 1] = excl + v0;
    cur[b * CPAD + 2 * t] = excl;
    cur[b * CPAD + 2 * t + 1] = excl + v0;
}

__global__ __launch_bounds__(256) void k_scatter(const float* __restrict__ xyz,
                                                 int* __restrict__ cur,
                                                 float4* __restrict__ pts) {
    int i = blockIdx.x * 256 + threadIdx.x;
    int b = i >> 14;
    const float* p = xyz + (size_t)i * 3;
    float x = p[0], y = p[1], z = p[2];
    int pos = atomicAdd(&cur[b * CPAD + cell_of(x, y, z)], 1);
    pts[(size_t)b * NN + pos] = make_float4(x, y, z, __int_as_float(i & (NN - 1)));
}

__global__ __launch_bounds__(256) void qgr_grid_kernel(
    const float* __restrict__ xyz,
    const float* __restrict__ nxyz,
    const int* __restrict__ offi,
    const float4* __restrict__ pts,
    float* __restrict__ out) {

    __shared__ float4 s_hit[4][2][HCAP];   // 16 KB: hit (x,y,z,idx-bits)
    __shared__ float4 s_sel[4][2][NS];     // 4 KB: selected 32, slot order

    const int lane = threadIdx.x & 63;
    const int w = threadIdx.x >> 6;
    const int sub = lane & 31;
    const int half = lane >> 5;
    const int q0 = blockIdx.x * 8 + w * 2;     // even; q0,q0+1 share batch b
    const int b = q0 >> 11;

    const float* xb = xyz + (size_t)b * NN * 3;
    const float* nq = nxyz + (size_t)q0 * 3;
    const float cx0 = nq[0], cy0 = nq[1], cz0 = nq[2];
    const float cx1 = nq[3], cy1 = nq[4], cz1 = nq[5];
    const unsigned long long lmask = (1ull << lane) - 1ull;

    const int* offb = offi + b * CPAD;
    const float4* ptsb = pts + (size_t)b * NN;

    // ---- phase 1: full-wave scan, one query at a time ----
    int hits01[2];
    for (int tq = 0; tq < 2; ++tq) {
        const float ccx = tq ? cx1 : cx0;
        const float ccy = tq ? cy1 : cy0;
        const float ccz = tq ? cz1 : cz0;

        int ci0 = (int)(ccx * 10.0f); ci0 = ci0 < 0 ? 0 : (ci0 > 9 ? 9 : ci0);
        int cj0 = (int)(ccy * 10.0f); cj0 = cj0 < 0 ? 0 : (cj0 > 9 ? 9 : cj0);
        int ck0 = (int)(ccz * 20.0f); ck0 = ck0 < 0 ? 0 : (ck0 > 19 ? 19 : ck0);
        int zlo = ck0 > 2 ? ck0 - 2 : 0;
        int zhi = ck0 < 17 ? ck0 + 2 : 19;

        int rs[9], rl[9];
        #pragma unroll
        for (int r = 0; r < 9; ++r) { rs[r] = 0; rl[r] = 0; }
        int nr = 0;
        #pragma unroll
        for (int di = -1; di <= 1; ++di) {
            int ii = ci0 + di; if ((unsigned)ii > 9u) continue;
            #pragma unroll
            for (int dj = -1; dj <= 1; ++dj) {
                int jj = cj0 + dj; if ((unsigned)jj > 9u) continue;
                int base2 = (ii * 10 + jj) * GZ;
                int s0 = offb[base2 + zlo];
                int e0 = offb[base2 + zhi + 1];
                int len = e0 - s0;
                if (len > 0) { rs[nr] = s0; rl[nr] = len; ++nr; }
            }
        }

        float4 P[9];
        #pragma unroll
        for (int r = 0; r < 9; ++r) {
            int a = (lane < rl[r]) ? (rs[r] + lane) : 0;
            P[r] = ptsb[a];
        }

        int hits = 0;
        #pragma unroll
        for (int r = 0; r < 9; ++r) {
            float dx = __fsub_rn(ccx, P[r].x);
            float dy = __fsub_rn(ccy, P[r].y);
            float dz = __fsub_rn(ccz, P[r].z);
            float d2 = __fadd_rn(__fadd_rn(__fmul_rn(dx, dx), __fmul_rn(dy, dy)),
                                 __fmul_rn(dz, dz));
            bool hit = (lane < rl[r]) && (d2 < R2);
            unsigned long long bal = __ballot(hit);
            if (bal) {
                int rank = __popcll(bal & lmask);
                int slot = hits + rank;
                if (hit && slot < HCAP) s_hit[w][tq][slot] = P[r];
                hits += __popcll(bal);
            }
        }
        for (int r = 0; r < nr; ++r) {           // rare: ranges > 64
            for (int t0 = 64; t0 < rl[r]; t0 += 64) {
                int t = t0 + lane;
                bool act = t < rl[r];
                float4 Q = ptsb[rs[r] + (act ? t : 0)];
                float dx = __fsub_rn(ccx, Q.x);
                float dy = __fsub_rn(ccy, Q.y);
                float dz = __fsub_rn(ccz, Q.z);
                float d2 = __fadd_rn(__fadd_rn(__fmul_rn(dx, dx), __fmul_rn(dy, dy)),
                                     __fmul_rn(dz, dz));
                bool hit = act && (d2 < R2);
                unsigned long long bal = __ballot(hit);
                if (bal) {
                    int rank = __popcll(bal & lmask);
                    int slot = hits + rank;
                    if (hit && slot < HCAP) s_hit[w][tq][slot] = Q;
                    hits += __popcll(bal);
                }
            }
        }
        hits01[tq] = hits;
    }

    // ---- phase 2: each 32-lane half handles its own query ----
    const int hits = half ? hits01[1] : hits01[0];
    const int cap = hits < HCAP ? hits : HCAP;
    const float ccx = half ? cx1 : cx0;
    const float ccy = half ? cy1 : cy0;
    const float ccz = half ? cz1 : cz0;

    // 128-elem bitonic in 4 regs x 32 lanes (verified R7); key = idx<<8 | slot
    int key[4];
    #pragma unroll
    for (int r = 0; r < 4; ++r) {
        int e = r * 32 + sub;
        int idx_e = __float_as_int(s_hit[w][half][e].w);
        key[r] = (e < cap) ? ((idx_e << 8) | e) : 0x7fffffff;
    }

    #pragma unroll
    for (int k = 2; k <= 16; k <<= 1) {
        #pragma unroll
        for (int j = k >> 1; j > 0; j >>= 1) {
            bool lower = (sub & j) == 0;
            bool asc = (sub & k) == 0;
            bool keepmin = (lower == asc);
            #pragma unroll
            for (int r = 0; r < 4; ++r) {
                int p = __shfl_xor(key[r], j);
                key[r] = keepmin ? min(key[r], p) : max(key[r], p);
            }
        }
    }
    #pragma unroll
    for (int j = 16; j > 0; j >>= 1) {
        bool lower = (sub & j) == 0;
        #pragma unroll
        for (int r = 0; r < 4; ++r) {
            int p = __shfl_xor(key[r], j);
            bool asc = (r & 1) == 0;
            key[r] = (lower == asc) ? min(key[r], p) : max(key[r], p);
        }
    }
    {
        int t0 = min(key[0], key[1]); key[1] = max(key[0], key[1]); key[0] = t0;
        int t2 = max(key[2], key[3]); key[3] = min(key[2], key[3]); key[2] = t2;
    }
    #pragma unroll
    for (int j = 16; j > 0; j >>= 1) {
        bool lower = (sub & j) == 0;
        #pragma unroll
        for (int r = 0; r < 4; ++r) {
            int p = __shfl_xor(key[r], j);
            bool asc = (r & 2) == 0;
            key[r] = (lower == asc) ? min(key[r], p) : max(key[r], p);
        }
    }
    {
        int t0 = min(key[0], key[2]); key[2] = max(key[0], key[2]); key[0] = t0;
        int t1 = min(key[1], key[3]); key[3] = max(key[1], key[3]); key[1] = t1;
        t0 = min(key[0], key[1]); key[1] = max(key[0], key[1]); key[0] = t0;
        t1 = min(key[2], key[3]); key[3] = max(key[2], key[3]); key[2] = t1;
    }
    #pragma unroll
    for (int j = 16; j > 0; j >>= 1) {
        bool lower = (sub & j) == 0;
        #pragma unroll
        for (int r = 0; r < 4; ++r) {
            int p = __shfl_xor(key[r], j);
            key[r] = lower ? min(key[r], p) : max(key[r], p);
        }
    }

    // fetch selected points (smallest 32 indices, ascending), pad with slot 0
    const int found = hits < NS ? hits : NS;
    const int hbase = half << 5;
    float4 sel = make_float4(0.f, 0.f, 0.f, 0.f);
    if (sub < found) sel = s_hit[w][half][key[0] & 0xFF];
    float p0x, p0y, p0z;
    if (found == 0) { p0x = xb[0]; p0y = xb[1]; p0z = xb[2]; }
    else {
        p0x = __shfl(sel.x, hbase); p0y = __shfl(sel.y, hbase); p0z = __shfl(sel.z, hbase);
    }
    if (sub >= found) { sel.x = p0x; sel.y = p0y; sel.z = p0z; }
    const float hx = sel.x, hy = sel.y, hz = sel.z;

    // stage selected pts for broadcast reads
    s_sel[w][half][sub] = sel;

    // dis column j=sub via ds_read_b128 broadcasts (exact np op order)
    float v[NS];
    #pragma unroll
    for (int ii = 0; ii < NS; ++ii) {
        float4 B = s_sel[w][half][ii];
        float dx = __fsub_rn(B.x, hx);
        float dy = __fsub_rn(B.y, hy);
        float dz = __fsub_rn(B.z, hz);
        v[ii] = sqrtf(__fadd_rn(__fadd_rn(__fmul_rn(dx, dx), __fmul_rn(dy, dy)),
                                __fmul_rn(dz, dz)));
    }

    // row-sub sum in numpy pairwise-8 order; half-local argmax, first-occurrence
    float r8[8];
    #pragma unroll
    for (int t = 0; t < 8; ++t) {
        r8[t] = __fadd_rn(__fadd_rn(__fadd_rn(v[t], v[t + 8]), v[t + 16]), v[t + 24]);
    }
    float mv = __fadd_rn(__fadd_rn(__fadd_rn(r8[0], r8[1]), __fadd_rn(r8[2], r8[3])),
                         __fadd_rn(__fadd_rn(r8[4], r8[5]), __fadd_rn(r8[6], r8[7])));
    int mi = sub;
    #pragma unroll
    for (int off = 1; off < 32; off <<= 1) {
        float ov = __shfl_xor(mv, off);
        int oi = __shfl_xor(mi, off);
        if (ov > mv || (ov == mv && oi < mi)) { mv = ov; mi = oi; }
    }

    float4 T = s_sel[w][half][mi];
    const float tx = T.x, ty = T.y, tz = T.z;

    float ux = ccy * tz - ccz * ty, uy = ccz * tx - ccx * tz, uz = ccx * ty - ccy * tx;
    float vx = uy * ccz - uz * ccy, vy = uz * ccx - ux * ccz, vz = ux * ccy - uy * ccx;
    float vn = fmaxf(sqrtf(vx * vx + vy * vy + vz * vz), 1e-37f);
    float tnx = vx / vn, tny = vy / vn, tnz = vz / vn;

    float nrm = sqrtf(ccx * ccx + ccy * ccy + ccz * ccz);
    float dn = nrm + 1e-8f;
    float nnx = ccx / dn, nny = ccy / dn, nnz = ccz / dn;

    float ax = ccy * hz - ccz * hy, ay = ccz * hx - ccx * hz, az = ccx * hy - ccy * hx;
    float px = ay * ccz - az * ccy, py = az * ccx - ax * ccz, pz = ax * ccy - ay * ccx;
    float pn = fmaxf(sqrtf(px * px + py * py + pz * pz), 1e-37f);
    px /= pn; py /= pn; pz /= pn;

    float qx = py * tnz - pz * tny;
    float qy = pz * tnx - px * tnz;
    float qz = px * tny - py * tnx;
    float sinv = qx * nnx + qy * nny + qz * nnz;

    float gr = sqrtf(hx * hx + hy * hy + hz * hz);

    const int m_h = (q0 + half) & (MM - 1);
    const size_t rowstride = (size_t)MM * NS;
    const size_t obase = (((size_t)b * 33) * MM + m_h) * NS + sub;
    out[obase + 32 * rowstride] = gr;

    // per-lane ascending sort: Batcher odd-even mergesort, min/max CEs
    #pragma unroll
    for (int p = 1; p < NS; p <<= 1) {
        #pragma unroll
        for (int k = p; k >= 1; k >>= 1) {
            #pragma unroll
            for (int j = k & (p - 1); j + k < NS; j += 2 * k) {
                #pragma unroll
                for (int i = 0; i < k; ++i) {
                    if (i + j + k < NS) {
                        int x = i + j, y = i + j + k;
                        if ((x / (2 * p)) == (y / (2 * p))) {
                            float lo = fminf(v[x], v[y]);
                            v[y] = fmaxf(v[x], v[y]);
                            v[x] = lo;
                        }
                    }
                }
            }
        }
    }

    #pragma unroll
    for (int ii = 0; ii < NS; ++ii)
        out[obase + (size_t)ii * rowstride] = v[ii] * sinv;
}

// ---------------- fallback: verified brute-force scan (round-4) ----------------
#define CHUNKS 4
__global__ __launch_bounds__(256) void qgr_kernel(
    const float* __restrict__ xyz,
    const float* __restrict__ nxyz,
    float* __restrict__ out) {

    __shared__ float s_gx[4][NS], s_gy[4][NS], s_gz[4][NS];
    __shared__ float s_dis[4][NS][NS + 1];

    const int lane = threadIdx.x & 63;
    const int w = threadIdx.x >> 6;
    const int q = blockIdx.x * 4 + w;
    const int b = q >> 11;
    const int m = q & (MM - 1);

    const float* xb = xyz + (size_t)b * NN * 3;
    const float* nq = nxyz + (size_t)q * 3;
    const float cx = nq[0], cy = nq[1], cz = nq[2];
    const unsigned long long lmask = (1ull << lane) - 1ull;

    int cnt = 0;
    for (int base = 0; base < NN; base += 64 * CHUNKS) {
        float X[CHUNKS], Y[CHUNKS], Z[CHUNKS];
        #pragma unroll
        for (int c = 0; c < CHUNKS; ++c) {
            const float* p = xb + (size_t)(base + c * 64 + lane) * 3;
            X[c] = p[0]; Y[c] = p[1]; Z[c] = p[2];
        }
        bool in[CHUNKS];
        #pragma unroll
        for (int c = 0; c < CHUNKS; ++c) {
            float dx = __fsub_rn(cx, X[c]);
            float dy = __fsub_rn(cy, Y[c]);
            float dz = __fsub_rn(cz, Z[c]);
            float d2 = __fadd_rn(__fadd_rn(__fmul_rn(dx, dx), __fmul_rn(dy, dy)),
                                 __fmul_rn(dz, dz));
            in[c] = d2 < R2;
        }
        #pragma unroll
        for (int c = 0; c < CHUNKS; ++c) {
            unsigned long long bal = __ballot(in[c]);
            if (bal) {
                int rank = __popcll(bal & lmask);
                int slot = cnt + rank;
                if (in[c] && slot < NS) {
                    s_gx[w][slot] = X[c]; s_gy[w][slot] = Y[c]; s_gz[w][slot] = Z[c];
                }
                cnt += __popcll(bal);
            }
        }
        if (cnt >= NS) break;
    }
    __syncthreads();

    int found = cnt < NS ? cnt : NS;
    float p0x, p0y, p0z;
    if (found == 0) { p0x = xb[0]; p0y = xb[1]; p0z = xb[2]; }
    else            { p0x = s_gx[w][0]; p0y = s_gy[w][0]; p0z = s_gz[w][0]; }
    if (lane < NS && lane >= found) {
        s_gx[w][lane] = p0x; s_gy[w][lane] = p0y; s_gz[w][lane] = p0z;
    }
    __syncthreads();

    #pragma unroll
    for (int t = 0; t < 16; ++t) {
        int e = t * 64 + lane;
        int di = e >> 5, dj = e & 31;
        float dx = __fsub_rn(s_gx[w][di], s_gx[w][dj]);
        float dy = __fsub_rn(s_gy[w][di], s_gy[w][dj]);
        float dz = __fsub_rn(s_gz[w][di], s_gz[w][dj]);
        s_dis[w][di][dj] =
            sqrtf(__fadd_rn(__fadd_rn(__fmul_rn(dx, dx), __fmul_rn(dy, dy)), __fmul_rn(dz, dz)));
    }
    __syncthreads();

    {
        int i = lane & 31;
        float r[8];
        #pragma unroll
        for (int t = 0; t < 8; ++t) {
            r[t] = __fadd_rn(__fadd_rn(__fadd_rn(s_dis[w][i][t], s_dis[w][i][t + 8]),
                                        s_dis[w][i][t + 16]),
                             s_dis[w][i][t + 24]);
        }
        float mv = __fadd_rn(__fadd_rn(__fadd_rn(r[0], r[1]), __fadd_rn(r[2], r[3])),
                             __fadd_rn(__fadd_rn(r[4], r[5]), __fadd_rn(r[6], r[7])));
        int mi = i;
        #pragma unroll
        for (int off = 1; off < 64; off <<= 1) {
            float ov = __shfl_xor(mv, off);
            int oi = __shfl_xor(mi, off);
            if (ov > mv || (ov == mv && oi < mi)) { mv = ov; mi = oi; }
        }
        float tx = s_gx[w][mi], ty = s_gy[w][mi], tz = s_gz[w][mi];
        float ux = cy * tz - cz * ty, uy = cz * tx - cx * tz, uz = cx * ty - cy * tx;
        float vx = uy * cz - uz * cy, vy = uz * cx - ux * cz, vz = ux * cy - uy * cx;
        float vn = fmaxf(sqrtf(vx * vx + vy * vy + vz * vz), 1e-37f);
        float tnx = vx / vn, tny = vy / vn, tnz = vz / vn;
        float nr = sqrtf(cx * cx + cy * cy + cz * cz);
        float dn = nr + 1e-8f;
        float nnx = cx / dn, nny = cy / dn, nnz = cz / dn;
        int j = lane & 31;
        float gx = s_gx[w][j], gy = s_gy[w][j], gz = s_gz[w][j];
        float ax = cy * gz - cz * gy, ay = cz * gx - cx * gz, az = cx * gy - cy * gx;
        float px = ay * cz - az * cy, py = az * cx - ax * cz, pz = ax * cy - ay * cx;
        float pn = fmaxf(sqrtf(px * px + py * py + pz * pz), 1e-37f);
        px /= pn; py /= pn; pz /= pn;
        float qx = py * tnz - pz * tny;
        float qy = pz * tnx - px * tnz;
        float qz = px * tny - py * tnx;
        float sinv = qx * nnx + qy * nny + qz * nnz;
        float gr = sqrtf(gx * gx + gy * gy + gz * gz);
        const size_t rowstride = (size_t)MM * NS;
        const size_t obase = (((size_t)b * 33) * MM + m) * NS + j;
        if (lane < NS) out[obase + 32 * rowstride] = gr;
        float v[NS];
        #pragma unroll
        for (int ii = 0; ii < NS; ++ii) v[ii] = s_dis[w][ii][j];
        #pragma unroll
        for (int k = 2; k <= NS; k <<= 1) {
            #pragma unroll
            for (int jj = k >> 1; jj > 0; jj >>= 1) {
                #pragma unroll
                for (int ii = 0; ii < NS; ++ii) {
                    int ll = ii ^ jj;
                    if (ll > ii) {
                        bool up = ((ii & k) == 0);
                        float a = v[ii], c2 = v[ll];
                        bool sw = up ? (a > c2) : (a < c2);
                        if (sw) { v[ii] = c2; v[ll] = a; }
                    }
                }
            }
        }
        if (lane < NS) {
            #pragma unroll
            for (int ii = 0; ii < NS; ++ii)
                out[obase + (size_t)ii * rowstride] = v[ii] * sinv;
        }
    }
}

extern "C" void kernel_launch(void* const* d_in, const int* in_sizes, int n_in,
                              void* d_out, int out_size, void* d_ws, size_t ws_size,
                              hipStream_t stream) {
    (void)in_sizes; (void)n_in; (void)out_size;
    const float* xyz = (const float*)d_in[0];
    const float* nxyz = (const float*)d_in[1];
    float* out = (float*)d_out;

    if (d_ws != nullptr && ws_size >= WS_NEED) {
        char* ws = (char*)d_ws;
        int* off = (int*)ws;
        int* cur = (int*)(ws + WS_CUR_OFF);
        int* cnt = (int*)(ws + WS_CNT_OFF);
        float4* pts = (float4*)(ws + WS_PTS_OFF);

        hipMemsetAsync(cnt, 0, 32 * 1024, stream);
        k_count<<<(BB * NN) / 256, 256, 0, stream>>>(xyz, cnt);
        k_scan<<<BB, 1024, 0, stream>>>(cnt, off, cur);
        k_scatter<<<(BB * NN) / 256, 256, 0, stream>>>(xyz, cur, pts);
        // 8192 queries, 2 per wave, 4 waves/block -> 1024 blocks
        qgr_grid_kernel<<<(BB * MM) / 8, 256, 0, stream>>>(xyz, nxyz, off, pts, out);
    } else {
        qgr_kernel<<<(BB * MM) / 4, 256, 0, stream>>>(xyz, nxyz, out);
    }
}